// Round 3
// baseline (435.418 us; speedup 1.0000x reference)
//
#include <hip/hip_runtime.h>
#include <stdint.h>
#include <math.h>

typedef short short8 __attribute__((ext_vector_type(8)));
typedef float f32x4 __attribute__((ext_vector_type(4)));

// Problem constants
#define S_LEN   2048
#define DMODEL  2048
#define NHEADS  16
#define HDIM    128
#define NBATCH  2
#define BHTOT   32      // NBATCH*NHEADS
#define MROWS   4096    // NBATCH*S_LEN

// Workspace byte offsets (total ~89 MB)
#define XB_OFF   ((size_t)0)          // x bf16; reused as attn-output O
#define WQ_OFF   ((size_t)16777216)   // Wq bf16; reused for Wo bf16
#define WK_OFF   ((size_t)25165824)
#define WV_OFF   ((size_t)33554432)
#define Q_OFF    ((size_t)41943040)   // (bh,s,d) bf16
#define K_OFF    ((size_t)58720256)   // (bh,s,d) bf16
#define VT_OFF   ((size_t)75497472)   // (bh,d,s) bf16 (V pre-transposed)
#define COS_OFF  ((size_t)92274688)   // 2048*64 f32
#define SIN_OFF  ((size_t)92798976)   // 2048*64 f32

__device__ __forceinline__ unsigned short f2bf(float f) {
  unsigned int u = __float_as_uint(f);
  unsigned int r = (u + 0x7FFFu + ((u >> 16) & 1u)) >> 16;  // RTNE
  return (unsigned short)r;
}
__device__ __forceinline__ float bf2f(unsigned short b) {
  return __uint_as_float(((unsigned int)b) << 16);
}

// async global->LDS, 16B per lane; LDS dest = wave-uniform base + lane*16
__device__ __forceinline__ void gl_lds16(const unsigned short* g, unsigned short* l) {
  __builtin_amdgcn_global_load_lds(
      (const __attribute__((address_space(1))) unsigned int*)(g),
      (__attribute__((address_space(3))) unsigned int*)(l),
      16, 0, 0);
}

// ---------------- fp32 -> bf16 convert (vectorized) ----------------
__global__ __launch_bounds__(256) void k_cvt(const float* __restrict__ src,
                                             unsigned short* __restrict__ dst, int n4) {
  int i = blockIdx.x * 256 + threadIdx.x;
  if (i >= n4) return;
  float4 v = ((const float4*)src)[i];
  ushort4 o;
  o.x = f2bf(v.x); o.y = f2bf(v.y); o.z = f2bf(v.z); o.w = f2bf(v.w);
  ((ushort4*)dst)[i] = o;
}

// ---------------- RoPE cos/sin table: [s][j], j<64 ----------------
__global__ __launch_bounds__(256) void k_rope_table(float* __restrict__ ct,
                                                    float* __restrict__ st) {
  int i = blockIdx.x * 256 + threadIdx.x;   // 2048*64 total
  if (i >= S_LEN * 64) return;
  int s = i >> 6, j = i & 63;
  float inv = expf(-(float)(2 * j) * (9.210340371976184f / 128.0f));
  float ang = (float)s * inv;
  ct[i] = cosf(ang);
  st[i] = sinf(ang);
}

// ---------------- in-place RoPE on (bh, s, 128) bf16 ----------------
__global__ __launch_bounds__(256) void k_rope(unsigned short* __restrict__ t,
                                              const float* __restrict__ ct,
                                              const float* __restrict__ st,
                                              float scale, int shift) {
  int id = blockIdx.x * 256 + threadIdx.x;
  int row = id >> shift;               // bh*2048 + s
  int c = id & ((1 << shift) - 1);
  int s = row & (S_LEN - 1);
  unsigned short* base = t + (size_t)row * HDIM;
  if (c < 4) {
    short8 v1 = *(short8*)(base + c * 8);
    short8 v2 = *(short8*)(base + c * 8 + 32);
    int j0 = c * 8;
    const float* cb = ct + s * 64;
    const float* sb = st + s * 64;
    short8 o1, o2;
#pragma unroll
    for (int i = 0; i < 8; i++) {
      float x1 = bf2f((unsigned short)v1[i]);
      float x2 = bf2f((unsigned short)v2[i]);
      float c1 = cb[j0 + i],      s1 = sb[j0 + i];
      float c2 = cb[j0 + 32 + i], s2 = sb[j0 + 32 + i];
      o1[i] = (short)f2bf((x1 * c1 - x2 * s1) * scale);
      o2[i] = (short)f2bf((x2 * c2 + x1 * s2) * scale);
    }
    *(short8*)(base + c * 8) = o1;
    *(short8*)(base + c * 8 + 32) = o2;
  } else {
    int cc = 8 + (c - 4) * 2;   // passthrough chunks 8..15, scaled (Q only)
    short8 v1 = *(short8*)(base + cc * 8);
    short8 v2 = *(short8*)(base + cc * 8 + 8);
    short8 o1, o2;
#pragma unroll
    for (int i = 0; i < 8; i++) {
      o1[i] = (short)f2bf(bf2f((unsigned short)v1[i]) * scale);
      o2[i] = (short)f2bf(bf2f((unsigned short)v2[i]) * scale);
    }
    *(short8*)(base + cc * 8) = o1;
    *(short8*)(base + cc * 8 + 8) = o2;
  }
}

// ---------------- fused QKV projection GEMM (global_load_lds, m97 structure) ----------------
__global__ __launch_bounds__(256) void k_gemm_qkv(
    const unsigned short* __restrict__ xb,
    const unsigned short* __restrict__ wqb, const unsigned short* __restrict__ wkb,
    const unsigned short* __restrict__ wvb,
    const float* __restrict__ bq, const float* __restrict__ bk, const float* __restrict__ bv,
    unsigned short* __restrict__ qr, unsigned short* __restrict__ kr,
    unsigned short* __restrict__ vt) {
  __shared__ unsigned short As[128][64];   // linear (gl_lds requires contiguous dest)
  __shared__ unsigned short Bs[128][64];
  int m0 = blockIdx.x * 128;
  int n0g = blockIdx.y * 128;              // 0..6143
  int wsel = n0g >> 11;                    // 0=Q 1=K 2=V
  int nw0 = n0g & (DMODEL - 1);
  const unsigned short* W = (wsel == 0) ? wqb : (wsel == 1 ? wkb : wvb);
  const float* bias = (wsel == 0) ? bq : (wsel == 1 ? bk : bv);
  int tid = threadIdx.x, lane = tid & 63, wid = tid >> 6;
  int wr = wid >> 1, wc = wid & 1;
  int lq = lane & 15, lk = lane >> 4;
  int gr = wid * 32 + (lane >> 3);         // staging row (i=0)
  int gc = (lane & 7) * 8;                 // staging col

  f32x4 acc[4][4];
#pragma unroll
  for (int m = 0; m < 4; m++)
#pragma unroll
    for (int n = 0; n < 4; n++) { acc[m][n][0]=0.f; acc[m][n][1]=0.f; acc[m][n][2]=0.f; acc[m][n][3]=0.f; }

  for (int k0 = 0; k0 < DMODEL; k0 += 64) {
#pragma unroll
    for (int i = 0; i < 4; i++) {
      gl_lds16(xb + (size_t)(m0 + gr + i * 8) * DMODEL + k0 + gc, &As[wid * 32 + i * 8][0]);
      gl_lds16(W  + (size_t)(nw0 + gr + i * 8) * DMODEL + k0 + gc, &Bs[wid * 32 + i * 8][0]);
    }
    __syncthreads();   // drains vmcnt (loads->LDS) + barrier
#pragma unroll
    for (int kk = 0; kk < 2; kk++) {
      short8 af[4], bfr[4];
#pragma unroll
      for (int m = 0; m < 4; m++)
        af[m] = *(const short8*)&As[wr * 64 + m * 16 + lq][kk * 32 + lk * 8];
#pragma unroll
      for (int n = 0; n < 4; n++)
        bfr[n] = *(const short8*)&Bs[wc * 64 + n * 16 + lq][kk * 32 + lk * 8];
#pragma unroll
      for (int m = 0; m < 4; m++)
#pragma unroll
        for (int n = 0; n < 4; n++)
          acc[m][n] = __builtin_amdgcn_mfma_f32_16x16x32_bf16(af[m], bfr[n], acc[m][n], 0, 0, 0);
    }
    __syncthreads();   // all reads done before next stage overwrites
  }

#pragma unroll
  for (int n = 0; n < 4; n++) {
    int el = nw0 + wc * 64 + n * 16 + lq;
    float bi = bias[el];
    int hh = el >> 7, dd = el & 127;
#pragma unroll
    for (int m = 0; m < 4; m++) {
      int sg = m0 + wr * 64 + m * 16 + lk * 4;
      int b = sg >> 11, ss = sg & (S_LEN - 1);
      if (wsel < 2) {
        unsigned short* dst = (wsel == 0 ? qr : kr) +
                              ((size_t)(b * NHEADS + hh) * S_LEN + ss) * HDIM + dd;
#pragma unroll
        for (int r = 0; r < 4; r++) dst[(size_t)r * HDIM] = f2bf(acc[m][n][r] + bi);
      } else {
        ushort4 o;
        o.x = f2bf(acc[m][n][0] + bi); o.y = f2bf(acc[m][n][1] + bi);
        o.z = f2bf(acc[m][n][2] + bi); o.w = f2bf(acc[m][n][3] + bi);
        *(ushort4*)(vt + ((size_t)(b * NHEADS + hh) * HDIM + dd) * S_LEN + ss) = o;
      }
    }
  }
}

// ---------------- causal flash attention (fold-balanced, K-prefetch, V direct) ----------------
// Q pre-scaled by 1/sqrt(128). grid = (bh=32, fold=16); each block does q-tiles
// {fold, 31-fold} = 33 KV steps. K tile prefetched into regs during prior step's
// compute (T14); V read directly from global (bh,d,s) layout — L2/L3 resident.
__global__ __launch_bounds__(256) void k_attn(
    const unsigned short* __restrict__ qr, const unsigned short* __restrict__ kr,
    const unsigned short* __restrict__ vt, unsigned short* __restrict__ ob) {
  __shared__ unsigned short Ks[64][132];    // +4 pad: row stride 66 dw -> 2-way max (free)
  __shared__ unsigned short Ps[4][16][68];  // per-wave P round-trip
  int bh = blockIdx.x, fold = blockIdx.y;
  int b = bh >> 4, h = bh & 15;
  int tid = threadIdx.x, lane = tid & 63, w = tid >> 6;
  int lq = lane & 15, lk = lane >> 4;
  int krow = tid >> 2, kcol = (tid & 3) * 32;   // K staging: 64B/thread
  const unsigned short* kbh = kr + (size_t)bh * S_LEN * HDIM;
  const unsigned short* vbh = vt + (size_t)bh * HDIM * S_LEN;

  for (int hf = 0; hf < 2; hf++) {
    int qt = (hf == 0) ? fold : (31 - fold);
    int q0 = qt * 64;

    const unsigned short* qbase =
        qr + ((size_t)bh * S_LEN + q0 + w * 16 + lq) * HDIM + lk * 8;
    short8 qf[4];
#pragma unroll
    for (int ks = 0; ks < 4; ks++) qf[ks] = *(const short8*)(qbase + ks * 32);

    f32x4 acco[8];
#pragma unroll
    for (int nd = 0; nd < 8; nd++) { acco[nd][0]=0.f; acco[nd][1]=0.f; acco[nd][2]=0.f; acco[nd][3]=0.f; }
    float rm[4], rs[4];
#pragma unroll
    for (int r = 0; r < 4; r++) { rm[r] = -3.0e38f; rs[r] = 0.f; }

    // prefetch K tile 0
    int4 kpre[4];
#pragma unroll
    for (int j = 0; j < 4; j++)
      kpre[j] = *(const int4*)(kbh + (size_t)krow * HDIM + kcol + j * 8);

    for (int t = 0; t <= qt; t++) {
      int kv0 = t * 64;
      __syncthreads();                 // prev step's Ks reads done
#pragma unroll
      for (int j = 0; j < 4; j++)
        *(int4*)&Ks[krow][kcol + j * 8] = kpre[j];
      __syncthreads();
      if (t < qt) {                    // prefetch next K tile (hides under compute)
#pragma unroll
        for (int j = 0; j < 4; j++)
          kpre[j] = *(const int4*)(kbh + (size_t)(kv0 + 64 + krow) * HDIM + kcol + j * 8);
      }

      // S = Q K^T (16x64 per wave)
      f32x4 sacc[4];
#pragma unroll
      for (int n = 0; n < 4; n++) { sacc[n][0]=0.f; sacc[n][1]=0.f; sacc[n][2]=0.f; sacc[n][3]=0.f; }
#pragma unroll
      for (int ks = 0; ks < 4; ks++) {
#pragma unroll
        for (int n = 0; n < 4; n++) {
          short8 kf = *(const short8*)&Ks[n * 16 + lq][ks * 32 + lk * 8];
          sacc[n] = __builtin_amdgcn_mfma_f32_16x16x32_bf16(qf[ks], kf, sacc[n], 0, 0, 0);
        }
      }
      // causal mask on diagonal tile
      if (t == qt) {
#pragma unroll
        for (int n = 0; n < 4; n++)
#pragma unroll
          for (int r = 0; r < 4; r++) {
            int qrow = q0 + w * 16 + lk * 4 + r;
            int kvc = kv0 + n * 16 + lq;
            if (kvc > qrow) sacc[n][r] = -3.0e38f;
          }
      }
      // online softmax
      float pscale[4];
#pragma unroll
      for (int r = 0; r < 4; r++) {
        float mx = fmaxf(fmaxf(sacc[0][r], sacc[1][r]), fmaxf(sacc[2][r], sacc[3][r]));
        mx = fmaxf(mx, __shfl_xor(mx, 1, 64));
        mx = fmaxf(mx, __shfl_xor(mx, 2, 64));
        mx = fmaxf(mx, __shfl_xor(mx, 4, 64));
        mx = fmaxf(mx, __shfl_xor(mx, 8, 64));
        float mnew = fmaxf(rm[r], mx);
        float corr = __expf(rm[r] - mnew);
        rm[r] = mnew;
        float psum = 0.f;
#pragma unroll
        for (int n = 0; n < 4; n++) {
          float p = __expf(sacc[n][r] - mnew);
          sacc[n][r] = p;
          psum += p;
        }
        psum += __shfl_xor(psum, 1, 64);
        psum += __shfl_xor(psum, 2, 64);
        psum += __shfl_xor(psum, 4, 64);
        psum += __shfl_xor(psum, 8, 64);
        rs[r] = rs[r] * corr + psum;
        pscale[r] = corr;
      }
#pragma unroll
      for (int nd = 0; nd < 8; nd++)
#pragma unroll
        for (int r = 0; r < 4; r++) acco[nd][r] *= pscale[r];

      // P -> bf16 -> LDS (accumulator layout -> A-frag layout)
#pragma unroll
      for (int n = 0; n < 4; n++)
#pragma unroll
        for (int r = 0; r < 4; r++)
          Ps[w][lk * 4 + r][n * 16 + lq] = f2bf(sacc[n][r]);

      // PV: O += P @ V, V frags straight from global (bh,d,s)
#pragma unroll
      for (int ks2 = 0; ks2 < 2; ks2++) {
        short8 pa = *(const short8*)&Ps[w][lq][ks2 * 32 + lk * 8];
#pragma unroll
        for (int nd = 0; nd < 8; nd++) {
          short8 vf = *(const short8*)(vbh + (size_t)(nd * 16 + lq) * S_LEN +
                                       kv0 + ks2 * 32 + lk * 8);
          acco[nd] = __builtin_amdgcn_mfma_f32_16x16x32_bf16(pa, vf, acco[nd], 0, 0, 0);
        }
      }
    }

    // normalize + store O as (b, s, e) bf16
#pragma unroll
    for (int r = 0; r < 4; r++) {
      float inv = 1.0f / rs[r];
      int srow = q0 + w * 16 + lk * 4 + r;
      unsigned short* dst = ob + ((size_t)b * S_LEN + srow) * DMODEL + h * HDIM;
#pragma unroll
      for (int nd = 0; nd < 8; nd++) dst[nd * 16 + lq] = f2bf(acco[nd][r] * inv);
    }
  }
}

// ---------------- output projection GEMM (global_load_lds, fp32 out) ----------------
__global__ __launch_bounds__(256) void k_gemm_out(
    const unsigned short* __restrict__ ob, const unsigned short* __restrict__ wob,
    const float* __restrict__ bo, float* __restrict__ out) {
  __shared__ unsigned short As[128][64];
  __shared__ unsigned short Bs[128][64];
  int m0 = blockIdx.x * 128, n0 = blockIdx.y * 128;
  int tid = threadIdx.x, lane = tid & 63, wid = tid >> 6;
  int wr = wid >> 1, wc = wid & 1;
  int lq = lane & 15, lk = lane >> 4;
  int gr = wid * 32 + (lane >> 3);
  int gc = (lane & 7) * 8;

  f32x4 acc[4][4];
#pragma unroll
  for (int m = 0; m < 4; m++)
#pragma unroll
    for (int n = 0; n < 4; n++) { acc[m][n][0]=0.f; acc[m][n][1]=0.f; acc[m][n][2]=0.f; acc[m][n][3]=0.f; }

  for (int k0 = 0; k0 < DMODEL; k0 += 64) {
#pragma unroll
    for (int i = 0; i < 4; i++) {
      gl_lds16(ob  + (size_t)(m0 + gr + i * 8) * DMODEL + k0 + gc, &As[wid * 32 + i * 8][0]);
      gl_lds16(wob + (size_t)(n0 + gr + i * 8) * DMODEL + k0 + gc, &Bs[wid * 32 + i * 8][0]);
    }
    __syncthreads();
#pragma unroll
    for (int kk = 0; kk < 2; kk++) {
      short8 af[4], bfr[4];
#pragma unroll
      for (int m = 0; m < 4; m++)
        af[m] = *(const short8*)&As[wr * 64 + m * 16 + lq][kk * 32 + lk * 8];
#pragma unroll
      for (int n = 0; n < 4; n++)
        bfr[n] = *(const short8*)&Bs[wc * 64 + n * 16 + lq][kk * 32 + lk * 8];
#pragma unroll
      for (int m = 0; m < 4; m++)
#pragma unroll
        for (int n = 0; n < 4; n++)
          acc[m][n] = __builtin_amdgcn_mfma_f32_16x16x32_bf16(af[m], bfr[n], acc[m][n], 0, 0, 0);
    }
    __syncthreads();
  }
#pragma unroll
  for (int n = 0; n < 4; n++) {
    int el = n0 + wc * 64 + n * 16 + lq;
    float bi = bo[el];
#pragma unroll
    for (int m = 0; m < 4; m++) {
      int row = m0 + wr * 64 + m * 16 + lk * 4;
#pragma unroll
      for (int r = 0; r < 4; r++)
        out[(size_t)(row + r) * DMODEL + el] = acc[m][n][r] + bi;
    }
  }
}

extern "C" void kernel_launch(void* const* d_in, const int* in_sizes, int n_in,
                              void* d_out, int out_size, void* d_ws, size_t ws_size,
                              hipStream_t stream) {
  const float* x  = (const float*)d_in[0];
  const float* Wq = (const float*)d_in[2];
  const float* bq = (const float*)d_in[3];
  const float* Wk = (const float*)d_in[4];
  const float* bk = (const float*)d_in[5];
  const float* Wv = (const float*)d_in[6];
  const float* bv = (const float*)d_in[7];
  const float* Wo = (const float*)d_in[8];
  const float* bo = (const float*)d_in[9];
  float* out = (float*)d_out;
  char* ws = (char*)d_ws;

  unsigned short* xb  = (unsigned short*)(ws + XB_OFF);
  unsigned short* wqb = (unsigned short*)(ws + WQ_OFF);
  unsigned short* wkb = (unsigned short*)(ws + WK_OFF);
  unsigned short* wvb = (unsigned short*)(ws + WV_OFF);
  unsigned short* qr  = (unsigned short*)(ws + Q_OFF);
  unsigned short* kr  = (unsigned short*)(ws + K_OFF);
  unsigned short* vt  = (unsigned short*)(ws + VT_OFF);
  float* ct = (float*)(ws + COS_OFF);
  float* st = (float*)(ws + SIN_OFF);

  k_cvt<<<(MROWS * DMODEL / 4 + 255) / 256, 256, 0, stream>>>(x, xb, MROWS * DMODEL / 4);
  k_cvt<<<(DMODEL * DMODEL / 4 + 255) / 256, 256, 0, stream>>>(Wq, wqb, DMODEL * DMODEL / 4);
  k_cvt<<<(DMODEL * DMODEL / 4 + 255) / 256, 256, 0, stream>>>(Wk, wkb, DMODEL * DMODEL / 4);
  k_cvt<<<(DMODEL * DMODEL / 4 + 255) / 256, 256, 0, stream>>>(Wv, wvb, DMODEL * DMODEL / 4);
  k_rope_table<<<(S_LEN * 64 + 255) / 256, 256, 0, stream>>>(ct, st);
  k_gemm_qkv<<<dim3(MROWS / 128, 6144 / 128), 256, 0, stream>>>(
      xb, wqb, wkb, wvb, bq, bk, bv, qr, kr, vt);
  k_cvt<<<(DMODEL * DMODEL / 4 + 255) / 256, 256, 0, stream>>>(Wo, wqb, DMODEL * DMODEL / 4);
  k_rope<<<(BHTOT * S_LEN * 8) / 256, 256, 0, stream>>>(qr, ct, st, 0.08838834764831843f, 3);
  k_rope<<<(BHTOT * S_LEN * 4) / 256, 256, 0, stream>>>(kr, ct, st, 1.0f, 2);
  k_attn<<<dim3(BHTOT, 16), 256, 0, stream>>>(qr, kr, vt, xb);
  k_gemm_out<<<dim3(MROWS / 128, DMODEL / 128), 256, 0, stream>>>(xb, wqb, bo, out);
}

// Round 4
// 384.167 us; speedup vs baseline: 1.1334x; 1.1334x over previous
//
#include <hip/hip_runtime.h>
#include <stdint.h>
#include <math.h>

typedef short short8 __attribute__((ext_vector_type(8)));
typedef float f32x4 __attribute__((ext_vector_type(4)));

// Problem constants
#define S_LEN   2048
#define DMODEL  2048
#define NHEADS  16
#define HDIM    128
#define NBATCH  2
#define BHTOT   32      // NBATCH*NHEADS
#define MROWS   4096    // NBATCH*S_LEN

// Workspace byte offsets (total ~89 MB)
#define XB_OFF   ((size_t)0)          // x bf16; reused as attn-output O
#define WQ_OFF   ((size_t)16777216)   // Wq bf16; reused for Wo bf16
#define WK_OFF   ((size_t)25165824)
#define WV_OFF   ((size_t)33554432)
#define Q_OFF    ((size_t)41943040)   // (bh,s,d) bf16
#define K_OFF    ((size_t)58720256)   // (bh,s,d) bf16
#define VT_OFF   ((size_t)75497472)   // (bh,d,s) bf16 (V pre-transposed)
#define COS_OFF  ((size_t)92274688)   // 2048*64 f32
#define SIN_OFF  ((size_t)92798976)   // 2048*64 f32

__device__ __forceinline__ unsigned short f2bf(float f) {
  unsigned int u = __float_as_uint(f);
  unsigned int r = (u + 0x7FFFu + ((u >> 16) & 1u)) >> 16;  // RTNE
  return (unsigned short)r;
}
__device__ __forceinline__ float bf2f(unsigned short b) {
  return __uint_as_float(((unsigned int)b) << 16);
}

// async global->LDS, 16B per lane; LDS dest = wave-uniform base + lane*16
__device__ __forceinline__ void gl_lds16(const unsigned short* g, unsigned short* l) {
  __builtin_amdgcn_global_load_lds(
      (const __attribute__((address_space(1))) unsigned int*)(g),
      (__attribute__((address_space(3))) unsigned int*)(l),
      16, 0, 0);
}

// ---------------- fp32 -> bf16 convert (vectorized) ----------------
__global__ __launch_bounds__(256) void k_cvt(const float* __restrict__ src,
                                             unsigned short* __restrict__ dst, int n4) {
  int i = blockIdx.x * 256 + threadIdx.x;
  if (i >= n4) return;
  float4 v = ((const float4*)src)[i];
  ushort4 o;
  o.x = f2bf(v.x); o.y = f2bf(v.y); o.z = f2bf(v.z); o.w = f2bf(v.w);
  ((ushort4*)dst)[i] = o;
}

// ---------------- RoPE cos/sin table: [s][j], j<64 ----------------
__global__ __launch_bounds__(256) void k_rope_table(float* __restrict__ ct,
                                                    float* __restrict__ st) {
  int i = blockIdx.x * 256 + threadIdx.x;   // 2048*64 total
  if (i >= S_LEN * 64) return;
  int s = i >> 6, j = i & 63;
  float inv = expf(-(float)(2 * j) * (9.210340371976184f / 128.0f));
  float ang = (float)s * inv;
  ct[i] = cosf(ang);
  st[i] = sinf(ang);
}

// ---------------- in-place RoPE on (bh, s, 128) bf16 ----------------
__global__ __launch_bounds__(256) void k_rope(unsigned short* __restrict__ t,
                                              const float* __restrict__ ct,
                                              const float* __restrict__ st,
                                              float scale, int shift) {
  int id = blockIdx.x * 256 + threadIdx.x;
  int row = id >> shift;               // bh*2048 + s
  int c = id & ((1 << shift) - 1);
  int s = row & (S_LEN - 1);
  unsigned short* base = t + (size_t)row * HDIM;
  if (c < 4) {
    short8 v1 = *(short8*)(base + c * 8);
    short8 v2 = *(short8*)(base + c * 8 + 32);
    int j0 = c * 8;
    const float* cb = ct + s * 64;
    const float* sb = st + s * 64;
    short8 o1, o2;
#pragma unroll
    for (int i = 0; i < 8; i++) {
      float x1 = bf2f((unsigned short)v1[i]);
      float x2 = bf2f((unsigned short)v2[i]);
      float c1 = cb[j0 + i],      s1 = sb[j0 + i];
      float c2 = cb[j0 + 32 + i], s2 = sb[j0 + 32 + i];
      o1[i] = (short)f2bf((x1 * c1 - x2 * s1) * scale);
      o2[i] = (short)f2bf((x2 * c2 + x1 * s2) * scale);
    }
    *(short8*)(base + c * 8) = o1;
    *(short8*)(base + c * 8 + 32) = o2;
  } else {
    int cc = 8 + (c - 4) * 2;   // passthrough chunks 8..15, scaled (Q only)
    short8 v1 = *(short8*)(base + cc * 8);
    short8 v2 = *(short8*)(base + cc * 8 + 8);
    short8 o1, o2;
#pragma unroll
    for (int i = 0; i < 8; i++) {
      o1[i] = (short)f2bf(bf2f((unsigned short)v1[i]) * scale);
      o2[i] = (short)f2bf(bf2f((unsigned short)v2[i]) * scale);
    }
    *(short8*)(base + cc * 8) = o1;
    *(short8*)(base + cc * 8 + 8) = o2;
  }
}

// ---------------- fused QKV projection GEMM ----------------
// global_load_lds staging (linear LDS dest) + both-sides XOR swizzle:
// LDS(row, c) holds global elem (row, c ^ ((row&7)<<3)); frag reads apply the
// same XOR -> 16-way read conflict becomes 2-way (free).  [rule #21 / T2]
__global__ __launch_bounds__(256) void k_gemm_qkv(
    const unsigned short* __restrict__ xb,
    const unsigned short* __restrict__ wqb, const unsigned short* __restrict__ wkb,
    const unsigned short* __restrict__ wvb,
    const float* __restrict__ bq, const float* __restrict__ bk, const float* __restrict__ bv,
    unsigned short* __restrict__ qr, unsigned short* __restrict__ kr,
    unsigned short* __restrict__ vt) {
  __shared__ unsigned short As[128][64];
  __shared__ unsigned short Bs[128][64];
  int m0 = blockIdx.x * 128;
  int n0g = blockIdx.y * 128;              // 0..6143
  int wsel = n0g >> 11;                    // 0=Q 1=K 2=V
  int nw0 = n0g & (DMODEL - 1);
  const unsigned short* W = (wsel == 0) ? wqb : (wsel == 1 ? wkb : wvb);
  const float* bias = (wsel == 0) ? bq : (wsel == 1 ? bk : bv);
  int tid = threadIdx.x, lane = tid & 63, wid = tid >> 6;
  int wr = wid >> 1, wc = wid & 1;
  int lq = lane & 15, lk = lane >> 4;
  int gr = wid * 32 + (lane >> 3);                       // staging row (i=0)
  int gc = ((lane & 7) * 8) ^ ((lane >> 3) << 3);        // pre-swizzled source col

  f32x4 acc[4][4];
#pragma unroll
  for (int m = 0; m < 4; m++)
#pragma unroll
    for (int n = 0; n < 4; n++) { acc[m][n][0]=0.f; acc[m][n][1]=0.f; acc[m][n][2]=0.f; acc[m][n][3]=0.f; }

  for (int k0 = 0; k0 < DMODEL; k0 += 64) {
#pragma unroll
    for (int i = 0; i < 4; i++) {
      gl_lds16(xb + (size_t)(m0 + gr + i * 8) * DMODEL + k0 + gc, &As[wid * 32 + i * 8][0]);
      gl_lds16(W  + (size_t)(nw0 + gr + i * 8) * DMODEL + k0 + gc, &Bs[wid * 32 + i * 8][0]);
    }
    __syncthreads();   // drains vmcnt (loads->LDS) + barrier
#pragma unroll
    for (int kk = 0; kk < 2; kk++) {
      short8 af[4], bfr[4];
      int sw = (lq & 7) << 3;          // row&7 == lq&7 for all frag rows
#pragma unroll
      for (int m = 0; m < 4; m++)
        af[m] = *(const short8*)&As[wr * 64 + m * 16 + lq][(kk * 32 + lk * 8) ^ sw];
#pragma unroll
      for (int n = 0; n < 4; n++)
        bfr[n] = *(const short8*)&Bs[wc * 64 + n * 16 + lq][(kk * 32 + lk * 8) ^ sw];
#pragma unroll
      for (int m = 0; m < 4; m++)
#pragma unroll
        for (int n = 0; n < 4; n++)
          acc[m][n] = __builtin_amdgcn_mfma_f32_16x16x32_bf16(af[m], bfr[n], acc[m][n], 0, 0, 0);
    }
    __syncthreads();   // all reads done before next stage overwrites
  }

#pragma unroll
  for (int n = 0; n < 4; n++) {
    int el = nw0 + wc * 64 + n * 16 + lq;
    float bi = bias[el];
    int hh = el >> 7, dd = el & 127;
#pragma unroll
    for (int m = 0; m < 4; m++) {
      int sg = m0 + wr * 64 + m * 16 + lk * 4;
      int b = sg >> 11, ss = sg & (S_LEN - 1);
      if (wsel < 2) {
        unsigned short* dst = (wsel == 0 ? qr : kr) +
                              ((size_t)(b * NHEADS + hh) * S_LEN + ss) * HDIM + dd;
#pragma unroll
        for (int r = 0; r < 4; r++) dst[(size_t)r * HDIM] = f2bf(acc[m][n][r] + bi);
      } else {
        ushort4 o;
        o.x = f2bf(acc[m][n][0] + bi); o.y = f2bf(acc[m][n][1] + bi);
        o.z = f2bf(acc[m][n][2] + bi); o.w = f2bf(acc[m][n][3] + bi);
        *(ushort4*)(vt + ((size_t)(b * NHEADS + hh) * HDIM + dd) * S_LEN + ss) = o;
      }
    }
  }
}

// ---------------- causal flash attention ----------------
// Fold-balanced grid + T14 async-stage: next K/V tile is loaded to REGISTERS
// right after the LDS-write barrier, so global latency hides under
// QK^T+softmax+PV; regs -> LDS after the next barrier. V staged in LDS
// (r3's direct-global V was a scattered gather: FETCH 2x, MfmaUtil down).
__global__ __launch_bounds__(256) void k_attn(
    const unsigned short* __restrict__ qr, const unsigned short* __restrict__ kr,
    const unsigned short* __restrict__ vt, unsigned short* __restrict__ ob) {
  __shared__ unsigned short Ks[64][136];    // kv x d (+8 pad -> 2-way, free)
  __shared__ unsigned short Vs[128][72];    // d x kv (+8 pad)
  __shared__ unsigned short Ps[4][16][72];  // per-wave P round-trip
  int bh = blockIdx.x, fold = blockIdx.y;
  int b = bh >> 4, h = bh & 15;
  int tid = threadIdx.x, lane = tid & 63, w = tid >> 6;
  int lq = lane & 15, lk = lane >> 4;
  int krow = tid >> 4, kcol = (tid & 15) * 8;   // K stage: 4 tiles of 16 rows
  int vrow = tid >> 3, vcol = (tid & 7) * 8;    // V stage: 4 tiles of 32 rows
  const unsigned short* kbh = kr + (size_t)bh * S_LEN * HDIM;
  const unsigned short* vbh = vt + (size_t)bh * HDIM * S_LEN;

  for (int hf = 0; hf < 2; hf++) {
    int qt = (hf == 0) ? fold : (31 - fold);
    int q0 = qt * 64;

    const unsigned short* qbase =
        qr + ((size_t)bh * S_LEN + q0 + w * 16 + lq) * HDIM + lk * 8;
    short8 qf[4];
#pragma unroll
    for (int ks = 0; ks < 4; ks++) qf[ks] = *(const short8*)(qbase + ks * 32);

    f32x4 acco[8];
#pragma unroll
    for (int nd = 0; nd < 8; nd++) { acco[nd][0]=0.f; acco[nd][1]=0.f; acco[nd][2]=0.f; acco[nd][3]=0.f; }
    float rm[4], rs[4];
#pragma unroll
    for (int r = 0; r < 4; r++) { rm[r] = -3.0e38f; rs[r] = 0.f; }

    // prefetch K/V tile 0 into registers
    int4 kpre[4], vpre[4];
#pragma unroll
    for (int i = 0; i < 4; i++) {
      kpre[i] = *(const int4*)(kbh + (size_t)(i * 16 + krow) * HDIM + kcol);
      vpre[i] = *(const int4*)(vbh + (size_t)(i * 32 + vrow) * S_LEN + vcol);
    }

    for (int t = 0; t <= qt; t++) {
      int kv0 = t * 64;
      __syncthreads();                 // prev step's LDS reads done
#pragma unroll
      for (int i = 0; i < 4; i++) {
        *(int4*)&Ks[i * 16 + krow][kcol] = kpre[i];
        *(int4*)&Vs[i * 32 + vrow][vcol] = vpre[i];
      }
      __syncthreads();
      if (t < qt) {                    // issue next-tile loads; hidden under compute
#pragma unroll
        for (int i = 0; i < 4; i++) {
          kpre[i] = *(const int4*)(kbh + (size_t)(kv0 + 64 + i * 16 + krow) * HDIM + kcol);
          vpre[i] = *(const int4*)(vbh + (size_t)(i * 32 + vrow) * S_LEN + kv0 + 64 + vcol);
        }
      }

      // S = Q K^T (16x64 per wave)
      f32x4 sacc[4];
#pragma unroll
      for (int n = 0; n < 4; n++) { sacc[n][0]=0.f; sacc[n][1]=0.f; sacc[n][2]=0.f; sacc[n][3]=0.f; }
#pragma unroll
      for (int ks = 0; ks < 4; ks++) {
#pragma unroll
        for (int n = 0; n < 4; n++) {
          short8 kf = *(const short8*)&Ks[n * 16 + lq][ks * 32 + lk * 8];
          sacc[n] = __builtin_amdgcn_mfma_f32_16x16x32_bf16(qf[ks], kf, sacc[n], 0, 0, 0);
        }
      }
      // causal mask on diagonal tile
      if (t == qt) {
#pragma unroll
        for (int n = 0; n < 4; n++)
#pragma unroll
          for (int r = 0; r < 4; r++) {
            int qrow = q0 + w * 16 + lk * 4 + r;
            int kvc = kv0 + n * 16 + lq;
            if (kvc > qrow) sacc[n][r] = -3.0e38f;
          }
      }
      // online softmax
      float pscale[4];
#pragma unroll
      for (int r = 0; r < 4; r++) {
        float mx = fmaxf(fmaxf(sacc[0][r], sacc[1][r]), fmaxf(sacc[2][r], sacc[3][r]));
        mx = fmaxf(mx, __shfl_xor(mx, 1, 64));
        mx = fmaxf(mx, __shfl_xor(mx, 2, 64));
        mx = fmaxf(mx, __shfl_xor(mx, 4, 64));
        mx = fmaxf(mx, __shfl_xor(mx, 8, 64));
        float mnew = fmaxf(rm[r], mx);
        float corr = __expf(rm[r] - mnew);
        rm[r] = mnew;
        float psum = 0.f;
#pragma unroll
        for (int n = 0; n < 4; n++) {
          float p = __expf(sacc[n][r] - mnew);
          sacc[n][r] = p;
          psum += p;
        }
        psum += __shfl_xor(psum, 1, 64);
        psum += __shfl_xor(psum, 2, 64);
        psum += __shfl_xor(psum, 4, 64);
        psum += __shfl_xor(psum, 8, 64);
        rs[r] = rs[r] * corr + psum;
        pscale[r] = corr;
      }
#pragma unroll
      for (int nd = 0; nd < 8; nd++)
#pragma unroll
        for (int r = 0; r < 4; r++) acco[nd][r] *= pscale[r];

      // P -> bf16 -> LDS (accumulator layout -> A-frag layout)
#pragma unroll
      for (int n = 0; n < 4; n++)
#pragma unroll
        for (int r = 0; r < 4; r++)
          Ps[w][lk * 4 + r][n * 16 + lq] = f2bf(sacc[n][r]);

      // PV: O += P @ V
#pragma unroll
      for (int ks2 = 0; ks2 < 2; ks2++) {
        short8 pa = *(const short8*)&Ps[w][lq][ks2 * 32 + lk * 8];
#pragma unroll
        for (int nd = 0; nd < 8; nd++) {
          short8 vf = *(const short8*)&Vs[nd * 16 + lq][ks2 * 32 + lk * 8];
          acco[nd] = __builtin_amdgcn_mfma_f32_16x16x32_bf16(pa, vf, acco[nd], 0, 0, 0);
        }
      }
    }

    // normalize + store O as (b, s, e) bf16
#pragma unroll
    for (int r = 0; r < 4; r++) {
      float inv = 1.0f / rs[r];
      int srow = q0 + w * 16 + lk * 4 + r;
      unsigned short* dst = ob + ((size_t)b * S_LEN + srow) * DMODEL + h * HDIM;
#pragma unroll
      for (int nd = 0; nd < 8; nd++) dst[nd * 16 + lq] = f2bf(acco[nd][r] * inv);
    }
  }
}

// ---------------- output projection GEMM (fp32 out) ----------------
__global__ __launch_bounds__(256) void k_gemm_out(
    const unsigned short* __restrict__ ob, const unsigned short* __restrict__ wob,
    const float* __restrict__ bo, float* __restrict__ out) {
  __shared__ unsigned short As[128][64];
  __shared__ unsigned short Bs[128][64];
  int m0 = blockIdx.x * 128, n0 = blockIdx.y * 128;
  int tid = threadIdx.x, lane = tid & 63, wid = tid >> 6;
  int wr = wid >> 1, wc = wid & 1;
  int lq = lane & 15, lk = lane >> 4;
  int gr = wid * 32 + (lane >> 3);
  int gc = ((lane & 7) * 8) ^ ((lane >> 3) << 3);

  f32x4 acc[4][4];
#pragma unroll
  for (int m = 0; m < 4; m++)
#pragma unroll
    for (int n = 0; n < 4; n++) { acc[m][n][0]=0.f; acc[m][n][1]=0.f; acc[m][n][2]=0.f; acc[m][n][3]=0.f; }

  for (int k0 = 0; k0 < DMODEL; k0 += 64) {
#pragma unroll
    for (int i = 0; i < 4; i++) {
      gl_lds16(ob  + (size_t)(m0 + gr + i * 8) * DMODEL + k0 + gc, &As[wid * 32 + i * 8][0]);
      gl_lds16(wob + (size_t)(n0 + gr + i * 8) * DMODEL + k0 + gc, &Bs[wid * 32 + i * 8][0]);
    }
    __syncthreads();
#pragma unroll
    for (int kk = 0; kk < 2; kk++) {
      short8 af[4], bfr[4];
      int sw = (lq & 7) << 3;
#pragma unroll
      for (int m = 0; m < 4; m++)
        af[m] = *(const short8*)&As[wr * 64 + m * 16 + lq][(kk * 32 + lk * 8) ^ sw];
#pragma unroll
      for (int n = 0; n < 4; n++)
        bfr[n] = *(const short8*)&Bs[wc * 64 + n * 16 + lq][(kk * 32 + lk * 8) ^ sw];
#pragma unroll
      for (int m = 0; m < 4; m++)
#pragma unroll
        for (int n = 0; n < 4; n++)
          acc[m][n] = __builtin_amdgcn_mfma_f32_16x16x32_bf16(af[m], bfr[n], acc[m][n], 0, 0, 0);
    }
    __syncthreads();
  }
#pragma unroll
  for (int n = 0; n < 4; n++) {
    int el = n0 + wc * 64 + n * 16 + lq;
    float bi = bo[el];
#pragma unroll
    for (int m = 0; m < 4; m++) {
      int row = m0 + wr * 64 + m * 16 + lk * 4;
#pragma unroll
      for (int r = 0; r < 4; r++)
        out[(size_t)(row + r) * DMODEL + el] = acc[m][n][r] + bi;
    }
  }
}

extern "C" void kernel_launch(void* const* d_in, const int* in_sizes, int n_in,
                              void* d_out, int out_size, void* d_ws, size_t ws_size,
                              hipStream_t stream) {
  const float* x  = (const float*)d_in[0];
  const float* Wq = (const float*)d_in[2];
  const float* bq = (const float*)d_in[3];
  const float* Wk = (const float*)d_in[4];
  const float* bk = (const float*)d_in[5];
  const float* Wv = (const float*)d_in[6];
  const float* bv = (const float*)d_in[7];
  const float* Wo = (const float*)d_in[8];
  const float* bo = (const float*)d_in[9];
  float* out = (float*)d_out;
  char* ws = (char*)d_ws;

  unsigned short* xb  = (unsigned short*)(ws + XB_OFF);
  unsigned short* wqb = (unsigned short*)(ws + WQ_OFF);
  unsigned short* wkb = (unsigned short*)(ws + WK_OFF);
  unsigned short* wvb = (unsigned short*)(ws + WV_OFF);
  unsigned short* qr  = (unsigned short*)(ws + Q_OFF);
  unsigned short* kr  = (unsigned short*)(ws + K_OFF);
  unsigned short* vt  = (unsigned short*)(ws + VT_OFF);
  float* ct = (float*)(ws + COS_OFF);
  float* st = (float*)(ws + SIN_OFF);

  k_cvt<<<(MROWS * DMODEL / 4 + 255) / 256, 256, 0, stream>>>(x, xb, MROWS * DMODEL / 4);
  k_cvt<<<(DMODEL * DMODEL / 4 + 255) / 256, 256, 0, stream>>>(Wq, wqb, DMODEL * DMODEL / 4);
  k_cvt<<<(DMODEL * DMODEL / 4 + 255) / 256, 256, 0, stream>>>(Wk, wkb, DMODEL * DMODEL / 4);
  k_cvt<<<(DMODEL * DMODEL / 4 + 255) / 256, 256, 0, stream>>>(Wv, wvb, DMODEL * DMODEL / 4);
  k_rope_table<<<(S_LEN * 64 + 255) / 256, 256, 0, stream>>>(ct, st);
  k_gemm_qkv<<<dim3(MROWS / 128, 6144 / 128), 256, 0, stream>>>(
      xb, wqb, wkb, wvb, bq, bk, bv, qr, kr, vt);
  k_cvt<<<(DMODEL * DMODEL / 4 + 255) / 256, 256, 0, stream>>>(Wo, wqb, DMODEL * DMODEL / 4);
  k_rope<<<(BHTOT * S_LEN * 8) / 256, 256, 0, stream>>>(qr, ct, st, 0.08838834764831843f, 3);
  k_rope<<<(BHTOT * S_LEN * 4) / 256, 256, 0, stream>>>(kr, ct, st, 1.0f, 2);
  k_attn<<<dim3(BHTOT, 16), 256, 0, stream>>>(qr, kr, vt, xb);
  k_gemm_out<<<dim3(MROWS / 128, DMODEL / 128), 256, 0, stream>>>(xb, wqb, bo, out);
}

// Round 5
// 291.811 us; speedup vs baseline: 1.4921x; 1.3165x over previous
//
#include <hip/hip_runtime.h>
#include <stdint.h>
#include <math.h>

typedef short short8 __attribute__((ext_vector_type(8)));
typedef float f32x4 __attribute__((ext_vector_type(4)));

// Problem constants
#define S_LEN   2048
#define DMODEL  2048
#define NHEADS  16
#define HDIM    128
#define NBATCH  2
#define BHTOT   32      // NBATCH*NHEADS
#define MROWS   4096    // NBATCH*S_LEN

// Workspace byte offsets (total ~89 MB)
#define XB_OFF   ((size_t)0)          // x bf16; reused as attn-output O
#define WQ_OFF   ((size_t)16777216)   // Wq bf16; reused for Wo bf16
#define WK_OFF   ((size_t)25165824)
#define WV_OFF   ((size_t)33554432)
#define Q_OFF    ((size_t)41943040)   // (bh,s,d) bf16
#define K_OFF    ((size_t)58720256)   // (bh,s,d) bf16
#define VT_OFF   ((size_t)75497472)   // (bh,d,s) bf16 (V pre-transposed)
#define COS_OFF  ((size_t)92274688)   // 2048*64 f32
#define SIN_OFF  ((size_t)92798976)   // 2048*64 f32

__device__ __forceinline__ unsigned short f2bf(float f) {
  unsigned int u = __float_as_uint(f);
  unsigned int r = (u + 0x7FFFu + ((u >> 16) & 1u)) >> 16;  // RTNE
  return (unsigned short)r;
}
__device__ __forceinline__ float bf2f(unsigned short b) {
  return __uint_as_float(((unsigned int)b) << 16);
}

// async global->LDS, 16B per lane; LDS dest = wave-uniform base + lane*16
__device__ __forceinline__ void gl_lds16(const unsigned short* g, unsigned short* l) {
  __builtin_amdgcn_global_load_lds(
      (const __attribute__((address_space(1))) unsigned int*)(g),
      (__attribute__((address_space(3))) unsigned int*)(l),
      16, 0, 0);
}

// ---------------- fp32 -> bf16 convert (vectorized) ----------------
__global__ __launch_bounds__(256) void k_cvt(const float* __restrict__ src,
                                             unsigned short* __restrict__ dst, int n4) {
  int i = blockIdx.x * 256 + threadIdx.x;
  if (i >= n4) return;
  float4 v = ((const float4*)src)[i];
  ushort4 o;
  o.x = f2bf(v.x); o.y = f2bf(v.y); o.z = f2bf(v.z); o.w = f2bf(v.w);
  ((ushort4*)dst)[i] = o;
}

// ---------------- RoPE cos/sin table: [s][j], j<64 ----------------
__global__ __launch_bounds__(256) void k_rope_table(float* __restrict__ ct,
                                                    float* __restrict__ st) {
  int i = blockIdx.x * 256 + threadIdx.x;   // 2048*64 total
  if (i >= S_LEN * 64) return;
  int s = i >> 6, j = i & 63;
  float inv = expf(-(float)(2 * j) * (9.210340371976184f / 128.0f));
  float ang = (float)s * inv;
  ct[i] = cosf(ang);
  st[i] = sinf(ang);
}

// ---------------- in-place RoPE on (bh, s, 128) bf16 ----------------
__global__ __launch_bounds__(256) void k_rope(unsigned short* __restrict__ t,
                                              const float* __restrict__ ct,
                                              const float* __restrict__ st,
                                              float scale, int shift) {
  int id = blockIdx.x * 256 + threadIdx.x;
  int row = id >> shift;               // bh*2048 + s
  int c = id & ((1 << shift) - 1);
  int s = row & (S_LEN - 1);
  unsigned short* base = t + (size_t)row * HDIM;
  if (c < 4) {
    short8 v1 = *(short8*)(base + c * 8);
    short8 v2 = *(short8*)(base + c * 8 + 32);
    int j0 = c * 8;
    const float* cb = ct + s * 64;
    const float* sb = st + s * 64;
    short8 o1, o2;
#pragma unroll
    for (int i = 0; i < 8; i++) {
      float x1 = bf2f((unsigned short)v1[i]);
      float x2 = bf2f((unsigned short)v2[i]);
      float c1 = cb[j0 + i],      s1 = sb[j0 + i];
      float c2 = cb[j0 + 32 + i], s2 = sb[j0 + 32 + i];
      o1[i] = (short)f2bf((x1 * c1 - x2 * s1) * scale);
      o2[i] = (short)f2bf((x2 * c2 + x1 * s2) * scale);
    }
    *(short8*)(base + c * 8) = o1;
    *(short8*)(base + c * 8 + 32) = o2;
  } else {
    int cc = 8 + (c - 4) * 2;   // passthrough chunks 8..15, scaled (Q only)
    short8 v1 = *(short8*)(base + cc * 8);
    short8 v2 = *(short8*)(base + cc * 8 + 8);
    short8 o1, o2;
#pragma unroll
    for (int i = 0; i < 8; i++) {
      o1[i] = (short)f2bf(bf2f((unsigned short)v1[i]) * scale);
      o2[i] = (short)f2bf(bf2f((unsigned short)v2[i]) * scale);
    }
    *(short8*)(base + cc * 8) = o1;
    *(short8*)(base + cc * 8 + 8) = o2;
  }
}

// ---------------- fused QKV projection GEMM ----------------
// global_load_lds staging (linear LDS dest) + both-sides XOR swizzle.
__global__ __launch_bounds__(256) void k_gemm_qkv(
    const unsigned short* __restrict__ xb,
    const unsigned short* __restrict__ wqb, const unsigned short* __restrict__ wkb,
    const unsigned short* __restrict__ wvb,
    const float* __restrict__ bq, const float* __restrict__ bk, const float* __restrict__ bv,
    unsigned short* __restrict__ qr, unsigned short* __restrict__ kr,
    unsigned short* __restrict__ vt) {
  __shared__ unsigned short As[128][64];
  __shared__ unsigned short Bs[128][64];
  int m0 = blockIdx.x * 128;
  int n0g = blockIdx.y * 128;              // 0..6143
  int wsel = n0g >> 11;                    // 0=Q 1=K 2=V
  int nw0 = n0g & (DMODEL - 1);
  const unsigned short* W = (wsel == 0) ? wqb : (wsel == 1 ? wkb : wvb);
  const float* bias = (wsel == 0) ? bq : (wsel == 1 ? bk : bv);
  int tid = threadIdx.x, lane = tid & 63, wid = tid >> 6;
  int wr = wid >> 1, wc = wid & 1;
  int lq = lane & 15, lk = lane >> 4;
  int gr = wid * 32 + (lane >> 3);                       // staging row (i=0)
  int gc = ((lane & 7) * 8) ^ ((lane >> 3) << 3);        // pre-swizzled source col

  f32x4 acc[4][4];
#pragma unroll
  for (int m = 0; m < 4; m++)
#pragma unroll
    for (int n = 0; n < 4; n++) { acc[m][n][0]=0.f; acc[m][n][1]=0.f; acc[m][n][2]=0.f; acc[m][n][3]=0.f; }

  for (int k0 = 0; k0 < DMODEL; k0 += 64) {
#pragma unroll
    for (int i = 0; i < 4; i++) {
      gl_lds16(xb + (size_t)(m0 + gr + i * 8) * DMODEL + k0 + gc, &As[wid * 32 + i * 8][0]);
      gl_lds16(W  + (size_t)(nw0 + gr + i * 8) * DMODEL + k0 + gc, &Bs[wid * 32 + i * 8][0]);
    }
    __syncthreads();   // drains vmcnt (loads->LDS) + barrier
#pragma unroll
    for (int kk = 0; kk < 2; kk++) {
      short8 af[4], bfr[4];
      int sw = (lq & 7) << 3;          // row&7 == lq&7 for all frag rows
#pragma unroll
      for (int m = 0; m < 4; m++)
        af[m] = *(const short8*)&As[wr * 64 + m * 16 + lq][(kk * 32 + lk * 8) ^ sw];
#pragma unroll
      for (int n = 0; n < 4; n++)
        bfr[n] = *(const short8*)&Bs[wc * 64 + n * 16 + lq][(kk * 32 + lk * 8) ^ sw];
#pragma unroll
      for (int m = 0; m < 4; m++)
#pragma unroll
        for (int n = 0; n < 4; n++)
          acc[m][n] = __builtin_amdgcn_mfma_f32_16x16x32_bf16(af[m], bfr[n], acc[m][n], 0, 0, 0);
    }
    __syncthreads();   // all reads done before next stage overwrites
  }

#pragma unroll
  for (int n = 0; n < 4; n++) {
    int el = nw0 + wc * 64 + n * 16 + lq;
    float bi = bias[el];
    int hh = el >> 7, dd = el & 127;
#pragma unroll
    for (int m = 0; m < 4; m++) {
      int sg = m0 + wr * 64 + m * 16 + lk * 4;
      int b = sg >> 11, ss = sg & (S_LEN - 1);
      if (wsel < 2) {
        unsigned short* dst = (wsel == 0 ? qr : kr) +
                              ((size_t)(b * NHEADS + hh) * S_LEN + ss) * HDIM + dd;
#pragma unroll
        for (int r = 0; r < 4; r++) dst[(size_t)r * HDIM] = f2bf(acc[m][n][r] + bi);
      } else {
        ushort4 o;
        o.x = f2bf(acc[m][n][0] + bi); o.y = f2bf(acc[m][n][1] + bi);
        o.z = f2bf(acc[m][n][2] + bi); o.w = f2bf(acc[m][n][3] + bi);
        *(ushort4*)(vt + ((size_t)(b * NHEADS + hh) * HDIM + dd) * S_LEN + ss) = o;
      }
    }
  }
}

// ---------------- causal flash attention ----------------
// Fold-balanced grid; T3 2-phase double-buffered global_load_lds staging:
// issue next K/V tile into buf^1 (DMA, zero VGPRs -> no spill), compute
// tile from buf, single __syncthreads (vmcnt drain + barrier), flip.
// LDS linear + both-sides XOR swizzle (pre-swizzled global source).
__global__ __launch_bounds__(256, 2) void k_attn(
    const unsigned short* __restrict__ qr, const unsigned short* __restrict__ kr,
    const unsigned short* __restrict__ vt, unsigned short* __restrict__ ob) {
  __shared__ unsigned short Kl[2][64 * 128];   // [kv][d] swizzled flat, dbuf
  __shared__ unsigned short Vl[2][128 * 64];   // [d][kv] swizzled flat, dbuf
  __shared__ unsigned short Ps[4][16][72];     // per-wave P round-trip
  int bh = blockIdx.x, fold = blockIdx.y;
  int b = bh >> 4, h = bh & 15;
  int tid = threadIdx.x, lane = tid & 63, w = tid >> 6;
  int lq = lane & 15, lk = lane >> 4;
  const unsigned short* kbh = kr + (size_t)bh * S_LEN * HDIM;
  const unsigned short* vbh = vt + (size_t)bh * HDIM * S_LEN;
  // staging: LDS-linear dest (c*2048 + tid*8 elems); source col pre-swizzled
  int ksrow = tid >> 4;                                   // + c*16
  int kscol = ((tid & 15) * 8) ^ ((ksrow & 7) << 3);
  int vsrow = tid >> 3;                                   // + c*32
  int vscol = ((tid & 7) * 8) ^ ((vsrow & 7) << 3);
  int ldso = tid * 8;
  int rsw = (lq & 7) << 3;                                // read-side XOR

  for (int hf = 0; hf < 2; hf++) {
    int qt = (hf == 0) ? fold : (31 - fold);
    int q0 = qt * 64;

    const unsigned short* qbase =
        qr + ((size_t)bh * S_LEN + q0 + w * 16 + lq) * HDIM + lk * 8;
    short8 qf[4];
#pragma unroll
    for (int ks = 0; ks < 4; ks++) qf[ks] = *(const short8*)(qbase + ks * 32);

    f32x4 acco[8];
#pragma unroll
    for (int nd = 0; nd < 8; nd++) { acco[nd][0]=0.f; acco[nd][1]=0.f; acco[nd][2]=0.f; acco[nd][3]=0.f; }
    float rm[4], rs[4];
#pragma unroll
    for (int r = 0; r < 4; r++) { rm[r] = -3.0e38f; rs[r] = 0.f; }

    // prologue: stage tile 0 into buf 0
#pragma unroll
    for (int c = 0; c < 4; c++) {
      gl_lds16(kbh + (size_t)(c * 16 + ksrow) * HDIM + kscol, &Kl[0][c * 2048 + ldso]);
      gl_lds16(vbh + (size_t)(c * 32 + vsrow) * S_LEN + vscol, &Vl[0][c * 2048 + ldso]);
    }
    __syncthreads();
    int cur = 0;

    for (int t = 0; t <= qt; t++) {
      int kv0 = t * 64;
      // issue next tile's DMA (stays in flight across the compute below)
      if (t < qt) {
        int nx = kv0 + 64;
#pragma unroll
        for (int c = 0; c < 4; c++) {
          gl_lds16(kbh + (size_t)(nx + c * 16 + ksrow) * HDIM + kscol,
                   &Kl[cur ^ 1][c * 2048 + ldso]);
          gl_lds16(vbh + (size_t)(c * 32 + vsrow) * S_LEN + nx + vscol,
                   &Vl[cur ^ 1][c * 2048 + ldso]);
        }
      }
      const unsigned short* K0 = &Kl[cur][0];
      const unsigned short* V0 = &Vl[cur][0];

      // S = Q K^T (16x64 per wave)
      f32x4 sacc[4];
#pragma unroll
      for (int n = 0; n < 4; n++) { sacc[n][0]=0.f; sacc[n][1]=0.f; sacc[n][2]=0.f; sacc[n][3]=0.f; }
#pragma unroll
      for (int ks = 0; ks < 4; ks++) {
#pragma unroll
        for (int n = 0; n < 4; n++) {
          short8 kf = *(const short8*)&K0[(n * 16 + lq) * 128 + ((ks * 32 + lk * 8) ^ rsw)];
          sacc[n] = __builtin_amdgcn_mfma_f32_16x16x32_bf16(qf[ks], kf, sacc[n], 0, 0, 0);
        }
      }
      // causal mask on diagonal tile
      if (t == qt) {
#pragma unroll
        for (int n = 0; n < 4; n++)
#pragma unroll
          for (int r = 0; r < 4; r++) {
            int qrow = q0 + w * 16 + lk * 4 + r;
            int kvc = kv0 + n * 16 + lq;
            if (kvc > qrow) sacc[n][r] = -3.0e38f;
          }
      }
      // online softmax
      float pscale[4];
#pragma unroll
      for (int r = 0; r < 4; r++) {
        float mx = fmaxf(fmaxf(sacc[0][r], sacc[1][r]), fmaxf(sacc[2][r], sacc[3][r]));
        mx = fmaxf(mx, __shfl_xor(mx, 1, 64));
        mx = fmaxf(mx, __shfl_xor(mx, 2, 64));
        mx = fmaxf(mx, __shfl_xor(mx, 4, 64));
        mx = fmaxf(mx, __shfl_xor(mx, 8, 64));
        float mnew = fmaxf(rm[r], mx);
        float corr = __expf(rm[r] - mnew);
        rm[r] = mnew;
        float psum = 0.f;
#pragma unroll
        for (int n = 0; n < 4; n++) {
          float p = __expf(sacc[n][r] - mnew);
          sacc[n][r] = p;
          psum += p;
        }
        psum += __shfl_xor(psum, 1, 64);
        psum += __shfl_xor(psum, 2, 64);
        psum += __shfl_xor(psum, 4, 64);
        psum += __shfl_xor(psum, 8, 64);
        rs[r] = rs[r] * corr + psum;
        pscale[r] = corr;
      }
#pragma unroll
      for (int nd = 0; nd < 8; nd++)
#pragma unroll
        for (int r = 0; r < 4; r++) acco[nd][r] *= pscale[r];

      // P -> bf16 -> LDS (accumulator layout -> A-frag layout; per-wave, no barrier)
#pragma unroll
      for (int n = 0; n < 4; n++)
#pragma unroll
        for (int r = 0; r < 4; r++)
          Ps[w][lk * 4 + r][n * 16 + lq] = f2bf(sacc[n][r]);

      // PV: O += P @ V
#pragma unroll
      for (int ks2 = 0; ks2 < 2; ks2++) {
        short8 pa = *(const short8*)&Ps[w][lq][ks2 * 32 + lk * 8];
#pragma unroll
        for (int nd = 0; nd < 8; nd++) {
          short8 vf = *(const short8*)&V0[(nd * 16 + lq) * 64 + ((ks2 * 32 + lk * 8) ^ rsw)];
          acco[nd] = __builtin_amdgcn_mfma_f32_16x16x32_bf16(pa, vf, acco[nd], 0, 0, 0);
        }
      }
      __syncthreads();   // drain next-tile DMA + barrier; buf ready
      cur ^= 1;
    }

    // normalize + store O as (b, s, e) bf16
#pragma unroll
    for (int r = 0; r < 4; r++) {
      float inv = 1.0f / rs[r];
      int srow = q0 + w * 16 + lk * 4 + r;
      unsigned short* dst = ob + ((size_t)b * S_LEN + srow) * DMODEL + h * HDIM;
#pragma unroll
      for (int nd = 0; nd < 8; nd++) dst[nd * 16 + lq] = f2bf(acco[nd][r] * inv);
    }
  }
}

// ---------------- output projection GEMM (fp32 out) ----------------
__global__ __launch_bounds__(256) void k_gemm_out(
    const unsigned short* __restrict__ ob, const unsigned short* __restrict__ wob,
    const float* __restrict__ bo, float* __restrict__ out) {
  __shared__ unsigned short As[128][64];
  __shared__ unsigned short Bs[128][64];
  int m0 = blockIdx.x * 128, n0 = blockIdx.y * 128;
  int tid = threadIdx.x, lane = tid & 63, wid = tid >> 6;
  int wr = wid >> 1, wc = wid & 1;
  int lq = lane & 15, lk = lane >> 4;
  int gr = wid * 32 + (lane >> 3);
  int gc = ((lane & 7) * 8) ^ ((lane >> 3) << 3);

  f32x4 acc[4][4];
#pragma unroll
  for (int m = 0; m < 4; m++)
#pragma unroll
    for (int n = 0; n < 4; n++) { acc[m][n][0]=0.f; acc[m][n][1]=0.f; acc[m][n][2]=0.f; acc[m][n][3]=0.f; }

  for (int k0 = 0; k0 < DMODEL; k0 += 64) {
#pragma unroll
    for (int i = 0; i < 4; i++) {
      gl_lds16(ob  + (size_t)(m0 + gr + i * 8) * DMODEL + k0 + gc, &As[wid * 32 + i * 8][0]);
      gl_lds16(wob + (size_t)(n0 + gr + i * 8) * DMODEL + k0 + gc, &Bs[wid * 32 + i * 8][0]);
    }
    __syncthreads();
#pragma unroll
    for (int kk = 0; kk < 2; kk++) {
      short8 af[4], bfr[4];
      int sw = (lq & 7) << 3;
#pragma unroll
      for (int m = 0; m < 4; m++)
        af[m] = *(const short8*)&As[wr * 64 + m * 16 + lq][(kk * 32 + lk * 8) ^ sw];
#pragma unroll
      for (int n = 0; n < 4; n++)
        bfr[n] = *(const short8*)&Bs[wc * 64 + n * 16 + lq][(kk * 32 + lk * 8) ^ sw];
#pragma unroll
      for (int m = 0; m < 4; m++)
#pragma unroll
        for (int n = 0; n < 4; n++)
          acc[m][n] = __builtin_amdgcn_mfma_f32_16x16x32_bf16(af[m], bfr[n], acc[m][n], 0, 0, 0);
    }
    __syncthreads();
  }
#pragma unroll
  for (int n = 0; n < 4; n++) {
    int el = n0 + wc * 64 + n * 16 + lq;
    float bi = bo[el];
#pragma unroll
    for (int m = 0; m < 4; m++) {
      int row = m0 + wr * 64 + m * 16 + lk * 4;
#pragma unroll
      for (int r = 0; r < 4; r++)
        out[(size_t)(row + r) * DMODEL + el] = acc[m][n][r] + bi;
    }
  }
}

extern "C" void kernel_launch(void* const* d_in, const int* in_sizes, int n_in,
                              void* d_out, int out_size, void* d_ws, size_t ws_size,
                              hipStream_t stream) {
  const float* x  = (const float*)d_in[0];
  const float* Wq = (const float*)d_in[2];
  const float* bq = (const float*)d_in[3];
  const float* Wk = (const float*)d_in[4];
  const float* bk = (const float*)d_in[5];
  const float* Wv = (const float*)d_in[6];
  const float* bv = (const float*)d_in[7];
  const float* Wo = (const float*)d_in[8];
  const float* bo = (const float*)d_in[9];
  float* out = (float*)d_out;
  char* ws = (char*)d_ws;

  unsigned short* xb  = (unsigned short*)(ws + XB_OFF);
  unsigned short* wqb = (unsigned short*)(ws + WQ_OFF);
  unsigned short* wkb = (unsigned short*)(ws + WK_OFF);
  unsigned short* wvb = (unsigned short*)(ws + WV_OFF);
  unsigned short* qr  = (unsigned short*)(ws + Q_OFF);
  unsigned short* kr  = (unsigned short*)(ws + K_OFF);
  unsigned short* vt  = (unsigned short*)(ws + VT_OFF);
  float* ct = (float*)(ws + COS_OFF);
  float* st = (float*)(ws + SIN_OFF);

  k_cvt<<<(MROWS * DMODEL / 4 + 255) / 256, 256, 0, stream>>>(x, xb, MROWS * DMODEL / 4);
  k_cvt<<<(DMODEL * DMODEL / 4 + 255) / 256, 256, 0, stream>>>(Wq, wqb, DMODEL * DMODEL / 4);
  k_cvt<<<(DMODEL * DMODEL / 4 + 255) / 256, 256, 0, stream>>>(Wk, wkb, DMODEL * DMODEL / 4);
  k_cvt<<<(DMODEL * DMODEL / 4 + 255) / 256, 256, 0, stream>>>(Wv, wvb, DMODEL * DMODEL / 4);
  k_rope_table<<<(S_LEN * 64 + 255) / 256, 256, 0, stream>>>(ct, st);
  k_gemm_qkv<<<dim3(MROWS / 128, 6144 / 128), 256, 0, stream>>>(
      xb, wqb, wkb, wvb, bq, bk, bv, qr, kr, vt);
  k_cvt<<<(DMODEL * DMODEL / 4 + 255) / 256, 256, 0, stream>>>(Wo, wqb, DMODEL * DMODEL / 4);
  k_rope<<<(BHTOT * S_LEN * 8) / 256, 256, 0, stream>>>(qr, ct, st, 0.08838834764831843f, 3);
  k_rope<<<(BHTOT * S_LEN * 4) / 256, 256, 0, stream>>>(kr, ct, st, 1.0f, 2);
  k_attn<<<dim3(BHTOT, 16), 256, 0, stream>>>(qr, kr, vt, xb);
  k_gemm_out<<<dim3(MROWS / 128, DMODEL / 128), 256, 0, stream>>>(xb, wqb, bo, out);
}

// Round 6
// 279.020 us; speedup vs baseline: 1.5605x; 1.0458x over previous
//
#include <hip/hip_runtime.h>
#include <stdint.h>
#include <math.h>

typedef short short8 __attribute__((ext_vector_type(8)));
typedef float f32x4 __attribute__((ext_vector_type(4)));

// Problem constants
#define S_LEN   2048
#define DMODEL  2048
#define NHEADS  16
#define HDIM    128
#define NBATCH  2
#define BHTOT   32      // NBATCH*NHEADS
#define MROWS   4096    // NBATCH*S_LEN

// Workspace byte offsets
#define XB_OFF   ((size_t)0)          // x bf16; reused as attn-output O
#define WQ_OFF   ((size_t)16777216)   // Wq bf16; reused for Wo bf16
#define WK_OFF   ((size_t)25165824)
#define WV_OFF   ((size_t)33554432)
#define Q_OFF    ((size_t)41943040)   // (bh,s,d) bf16
#define K_OFF    ((size_t)58720256)   // (bh,s,d) bf16
#define VT_OFF   ((size_t)75497472)   // (bh,d,s) bf16 (V pre-transposed)
#define COS_OFF  ((size_t)92274688)   // 2048*64 f32
#define SIN_OFF  ((size_t)92798976)   // 2048*64 f32

__device__ __forceinline__ unsigned short f2bf(float f) {
  unsigned int u = __float_as_uint(f);
  unsigned int r = (u + 0x7FFFu + ((u >> 16) & 1u)) >> 16;  // RTNE
  return (unsigned short)r;
}
__device__ __forceinline__ float bf2f(unsigned short b) {
  return __uint_as_float(((unsigned int)b) << 16);
}

// async global->LDS, 16B per lane; LDS dest = wave-uniform base + lane*16
__device__ __forceinline__ void gl_lds16(const unsigned short* g, unsigned short* l) {
  __builtin_amdgcn_global_load_lds(
      (const __attribute__((address_space(1))) unsigned int*)(g),
      (__attribute__((address_space(3))) unsigned int*)(l),
      16, 0, 0);
}

// ---------------- fp32 -> bf16 convert (vectorized) ----------------
__global__ __launch_bounds__(256) void k_cvt(const float* __restrict__ src,
                                             unsigned short* __restrict__ dst, int n4) {
  int i = blockIdx.x * 256 + threadIdx.x;
  if (i >= n4) return;
  float4 v = ((const float4*)src)[i];
  ushort4 o;
  o.x = f2bf(v.x); o.y = f2bf(v.y); o.z = f2bf(v.z); o.w = f2bf(v.w);
  ((ushort4*)dst)[i] = o;
}

// ---------------- 3-way weight convert (Wq/Wk/Wv in one launch) ----------------
__global__ __launch_bounds__(256) void k_cvtw(
    const float* __restrict__ s0, const float* __restrict__ s1, const float* __restrict__ s2,
    unsigned short* __restrict__ d0, unsigned short* __restrict__ d1,
    unsigned short* __restrict__ d2) {
  int i = blockIdx.x * 256 + threadIdx.x;     // 3 * 2^20 elements of float4
  int sel = i >> 20, off = i & 1048575;
  const float* s = (sel == 0) ? s0 : (sel == 1 ? s1 : s2);
  unsigned short* d = (sel == 0) ? d0 : (sel == 1 ? d1 : d2);
  float4 v = ((const float4*)s)[off];
  ushort4 o;
  o.x = f2bf(v.x); o.y = f2bf(v.y); o.z = f2bf(v.z); o.w = f2bf(v.w);
  ((ushort4*)d)[off] = o;
}

// ---------------- RoPE cos/sin table: [s][j], j<64 ----------------
__global__ __launch_bounds__(256) void k_rope_table(float* __restrict__ ct,
                                                    float* __restrict__ st) {
  int i = blockIdx.x * 256 + threadIdx.x;   // 2048*64 total
  if (i >= S_LEN * 64) return;
  int s = i >> 6, j = i & 63;
  float inv = expf(-(float)(2 * j) * (9.210340371976184f / 128.0f));
  float ang = (float)s * inv;
  ct[i] = cosf(ang);
  st[i] = sinf(ang);
}

// ---------------- fused QKV projection GEMM + RoPE + transpose epilogue ----------------
// global_load_lds staging (linear LDS) + both-sides XOR swizzle in the K-loop.
// Epilogue: bias + RoPE (Q also *1/sqrt(128)) computed in-register, written to a
// reused 128x136 LDS tile in the TARGET layout, then stored fully coalesced.
#define CP 136
__global__ __launch_bounds__(256) void k_gemm_qkv(
    const unsigned short* __restrict__ xb,
    const unsigned short* __restrict__ wqb, const unsigned short* __restrict__ wkb,
    const unsigned short* __restrict__ wvb,
    const float* __restrict__ bq, const float* __restrict__ bk, const float* __restrict__ bv,
    const float* __restrict__ ct, const float* __restrict__ st,
    unsigned short* __restrict__ qr, unsigned short* __restrict__ kr,
    unsigned short* __restrict__ vt) {
  __shared__ unsigned short SMEM[128 * CP];   // K-loop: As=SMEM[0:8192) Bs=[8192:16384); epilogue: Cs[128][CP]
  unsigned short* As = SMEM;
  unsigned short* Bs = SMEM + 8192;
  int m0 = blockIdx.x * 128;
  int n0g = blockIdx.y * 128;              // 0..6143
  int wsel = n0g >> 11;                    // 0=Q 1=K 2=V
  int nw0 = n0g & (DMODEL - 1);
  const unsigned short* W = (wsel == 0) ? wqb : (wsel == 1 ? wkb : wvb);
  const float* bias = (wsel == 0) ? bq : (wsel == 1 ? bk : bv);
  int tid = threadIdx.x, lane = tid & 63, wid = tid >> 6;
  int wr = wid >> 1, wc = wid & 1;
  int lq = lane & 15, lk = lane >> 4;
  int gr = wid * 32 + (lane >> 3);                       // staging row (i=0)
  int gc = ((lane & 7) * 8) ^ ((lane >> 3) << 3);        // pre-swizzled source col

  f32x4 acc[4][4];
#pragma unroll
  for (int m = 0; m < 4; m++)
#pragma unroll
    for (int n = 0; n < 4; n++) { acc[m][n][0]=0.f; acc[m][n][1]=0.f; acc[m][n][2]=0.f; acc[m][n][3]=0.f; }

  for (int k0 = 0; k0 < DMODEL; k0 += 64) {
#pragma unroll
    for (int i = 0; i < 4; i++) {
      gl_lds16(xb + (size_t)(m0 + gr + i * 8) * DMODEL + k0 + gc, As + (wid * 32 + i * 8) * 64);
      gl_lds16(W  + (size_t)(nw0 + gr + i * 8) * DMODEL + k0 + gc, Bs + (wid * 32 + i * 8) * 64);
    }
    __syncthreads();   // drains vmcnt (loads->LDS) + barrier
#pragma unroll
    for (int kk = 0; kk < 2; kk++) {
      short8 af[4], bfr[4];
      int sw = (lq & 7) << 3;          // row&7 == lq&7 for all frag rows
#pragma unroll
      for (int m = 0; m < 4; m++)
        af[m] = *(const short8*)&As[(wr * 64 + m * 16 + lq) * 64 + ((kk * 32 + lk * 8) ^ sw)];
#pragma unroll
      for (int n = 0; n < 4; n++)
        bfr[n] = *(const short8*)&Bs[(wc * 64 + n * 16 + lq) * 64 + ((kk * 32 + lk * 8) ^ sw)];
#pragma unroll
      for (int m = 0; m < 4; m++)
#pragma unroll
        for (int n = 0; n < 4; n++)
          acc[m][n] = __builtin_amdgcn_mfma_f32_16x16x32_bf16(af[m], bfr[n], acc[m][n], 0, 0, 0);
    }
    __syncthreads();   // all reads done before next stage overwrites
  }

  // ---- epilogue: bias (+RoPE for Q/K) -> Cs in target layout -> coalesced store
  int h = nw0 >> 7, b = m0 >> 11, s0 = m0 & (S_LEN - 1);
  float bi[4];
#pragma unroll
  for (int n = 0; n < 4; n++) bi[n] = bias[nw0 + wc * 64 + n * 16 + lq];

  if (wsel < 2) {
    float qs = (wsel == 0) ? 0.08838834764831843f : 1.0f;
    if (wc == 0) {
      // rope features f in [0,64): pair (f, f+32) = (acc[m][n], acc[m][n+2]), n in {0,1}
#pragma unroll
      for (int m = 0; m < 4; m++) {
        int sl = wr * 64 + m * 16 + lk * 4;
#pragma unroll
        for (int r = 0; r < 4; r++) {
          int s = (s0 + sl + r);
          const float* cb = ct + s * 64;
          const float* sb = st + s * 64;
#pragma unroll
          for (int n = 0; n < 2; n++) {
            int f = n * 16 + lq;
            float x1 = acc[m][n][r] + bi[n];
            float x2 = acc[m][n + 2][r] + bi[n + 2];
            SMEM[(sl + r) * CP + f]      = f2bf((x1 * cb[f]      - x2 * sb[f])      * qs);
            SMEM[(sl + r) * CP + f + 32] = f2bf((x2 * cb[f + 32] + x1 * sb[f + 32]) * qs);
          }
        }
      }
    } else {
      // passthrough features f in [64,128), scaled (Q) / copied (K)
#pragma unroll
      for (int m = 0; m < 4; m++) {
        int sl = wr * 64 + m * 16 + lk * 4;
#pragma unroll
        for (int n = 0; n < 4; n++) {
          int f = 64 + n * 16 + lq;
#pragma unroll
          for (int r = 0; r < 4; r++)
            SMEM[(sl + r) * CP + f] = f2bf((acc[m][n][r] + bi[n]) * qs);
        }
      }
    }
    __syncthreads();
    int row = tid >> 1, hf2 = tid & 1;    // row = local s
    unsigned short* dstb = (wsel == 0 ? qr : kr) +
        ((size_t)(b * NHEADS + h) * S_LEN + s0 + row) * HDIM + hf2 * 64;
    const unsigned short* srcb = &SMEM[row * CP + hf2 * 64];
#pragma unroll
    for (int j = 0; j < 8; j++)
      *(short8*)(dstb + j * 8) = *(const short8*)(srcb + j * 8);
  } else {
    // V: transpose to (d, s) within the tile
#pragma unroll
    for (int m = 0; m < 4; m++) {
      int sl = wr * 64 + m * 16 + lk * 4;
#pragma unroll
      for (int n = 0; n < 4; n++) {
        int f = wc * 64 + n * 16 + lq;
#pragma unroll
        for (int r = 0; r < 4; r++)
          SMEM[f * CP + sl + r] = f2bf(acc[m][n][r] + bi[n]);
      }
    }
    __syncthreads();
    int row = tid >> 1, hf2 = tid & 1;    // row = d
    unsigned short* dstb = vt +
        ((size_t)(b * NHEADS + h) * HDIM + row) * S_LEN + s0 + hf2 * 64;
    const unsigned short* srcb = &SMEM[row * CP + hf2 * 64];
#pragma unroll
    for (int j = 0; j < 8; j++)
      *(short8*)(dstb + j * 8) = *(const short8*)(srcb + j * 8);
  }
}

// ---------------- causal flash attention ----------------
// Fold-balanced grid; 2-phase double-buffered global_load_lds staging;
// both-sides XOR swizzle; defer-max (T13, THR=8) online softmax.
__global__ __launch_bounds__(256, 2) void k_attn(
    const unsigned short* __restrict__ qr, const unsigned short* __restrict__ kr,
    const unsigned short* __restrict__ vt, unsigned short* __restrict__ ob) {
  __shared__ unsigned short Kl[2][64 * 128];   // [kv][d] swizzled flat, dbuf
  __shared__ unsigned short Vl[2][128 * 64];   // [d][kv] swizzled flat, dbuf
  __shared__ unsigned short Ps[4][16][72];     // per-wave P round-trip
  int bh = blockIdx.x, fold = blockIdx.y;
  int b = bh >> 4, h = bh & 15;
  int tid = threadIdx.x, lane = tid & 63, w = tid >> 6;
  int lq = lane & 15, lk = lane >> 4;
  const unsigned short* kbh = kr + (size_t)bh * S_LEN * HDIM;
  const unsigned short* vbh = vt + (size_t)bh * HDIM * S_LEN;
  int ksrow = tid >> 4;
  int kscol = ((tid & 15) * 8) ^ ((ksrow & 7) << 3);
  int vsrow = tid >> 3;
  int vscol = ((tid & 7) * 8) ^ ((vsrow & 7) << 3);
  int ldso = tid * 8;
  int rsw = (lq & 7) << 3;

  for (int hf = 0; hf < 2; hf++) {
    int qt = (hf == 0) ? fold : (31 - fold);
    int q0 = qt * 64;

    const unsigned short* qbase =
        qr + ((size_t)bh * S_LEN + q0 + w * 16 + lq) * HDIM + lk * 8;
    short8 qf[4];
#pragma unroll
    for (int ks = 0; ks < 4; ks++) qf[ks] = *(const short8*)(qbase + ks * 32);

    f32x4 acco[8];
#pragma unroll
    for (int nd = 0; nd < 8; nd++) { acco[nd][0]=0.f; acco[nd][1]=0.f; acco[nd][2]=0.f; acco[nd][3]=0.f; }
    float rm[4], rs[4];
#pragma unroll
    for (int r = 0; r < 4; r++) { rm[r] = -3.0e38f; rs[r] = 0.f; }

#pragma unroll
    for (int c = 0; c < 4; c++) {
      gl_lds16(kbh + (size_t)(c * 16 + ksrow) * HDIM + kscol, &Kl[0][c * 2048 + ldso]);
      gl_lds16(vbh + (size_t)(c * 32 + vsrow) * S_LEN + vscol, &Vl[0][c * 2048 + ldso]);
    }
    __syncthreads();
    int cur = 0;

    for (int t = 0; t <= qt; t++) {
      int kv0 = t * 64;
      if (t < qt) {
        int nx = kv0 + 64;
#pragma unroll
        for (int c = 0; c < 4; c++) {
          gl_lds16(kbh + (size_t)(nx + c * 16 + ksrow) * HDIM + kscol,
                   &Kl[cur ^ 1][c * 2048 + ldso]);
          gl_lds16(vbh + (size_t)(c * 32 + vsrow) * S_LEN + nx + vscol,
                   &Vl[cur ^ 1][c * 2048 + ldso]);
        }
      }
      const unsigned short* K0 = &Kl[cur][0];
      const unsigned short* V0 = &Vl[cur][0];

      // S = Q K^T (16x64 per wave)
      f32x4 sacc[4];
#pragma unroll
      for (int n = 0; n < 4; n++) { sacc[n][0]=0.f; sacc[n][1]=0.f; sacc[n][2]=0.f; sacc[n][3]=0.f; }
#pragma unroll
      for (int ks = 0; ks < 4; ks++) {
#pragma unroll
        for (int n = 0; n < 4; n++) {
          short8 kf = *(const short8*)&K0[(n * 16 + lq) * 128 + ((ks * 32 + lk * 8) ^ rsw)];
          sacc[n] = __builtin_amdgcn_mfma_f32_16x16x32_bf16(qf[ks], kf, sacc[n], 0, 0, 0);
        }
      }
      if (t == qt) {
#pragma unroll
        for (int n = 0; n < 4; n++)
#pragma unroll
          for (int r = 0; r < 4; r++) {
            int qrow = q0 + w * 16 + lk * 4 + r;
            int kvc = kv0 + n * 16 + lq;
            if (kvc > qrow) sacc[n][r] = -3.0e38f;
          }
      }
      // online softmax with defer-max (skip rescale while max growth <= 8)
      float mx4[4];
      int need = 0;
#pragma unroll
      for (int r = 0; r < 4; r++) {
        float mx = fmaxf(fmaxf(sacc[0][r], sacc[1][r]), fmaxf(sacc[2][r], sacc[3][r]));
        mx = fmaxf(mx, __shfl_xor(mx, 1, 64));
        mx = fmaxf(mx, __shfl_xor(mx, 2, 64));
        mx = fmaxf(mx, __shfl_xor(mx, 4, 64));
        mx = fmaxf(mx, __shfl_xor(mx, 8, 64));
        mx4[r] = mx;
        need |= (mx - rm[r] > 8.0f) ? 1 : 0;
      }
      if (__any(need)) {
#pragma unroll
        for (int r = 0; r < 4; r++) {
          float mnew = fmaxf(rm[r], mx4[r]);
          float corr = __expf(rm[r] - mnew);
          rs[r] *= corr;
#pragma unroll
          for (int nd = 0; nd < 8; nd++) acco[nd][r] *= corr;
          rm[r] = mnew;
        }
      }
#pragma unroll
      for (int r = 0; r < 4; r++) {
        float psum = 0.f;
#pragma unroll
        for (int n = 0; n < 4; n++) {
          float p = __expf(sacc[n][r] - rm[r]);
          sacc[n][r] = p;
          psum += p;
        }
        psum += __shfl_xor(psum, 1, 64);
        psum += __shfl_xor(psum, 2, 64);
        psum += __shfl_xor(psum, 4, 64);
        psum += __shfl_xor(psum, 8, 64);
        rs[r] += psum;
      }

      // P -> bf16 -> LDS (accumulator layout -> A-frag layout; per-wave)
#pragma unroll
      for (int n = 0; n < 4; n++)
#pragma unroll
        for (int r = 0; r < 4; r++)
          Ps[w][lk * 4 + r][n * 16 + lq] = f2bf(sacc[n][r]);

      // PV: O += P @ V
#pragma unroll
      for (int ks2 = 0; ks2 < 2; ks2++) {
        short8 pa = *(const short8*)&Ps[w][lq][ks2 * 32 + lk * 8];
#pragma unroll
        for (int nd = 0; nd < 8; nd++) {
          short8 vf = *(const short8*)&V0[(nd * 16 + lq) * 64 + ((ks2 * 32 + lk * 8) ^ rsw)];
          acco[nd] = __builtin_amdgcn_mfma_f32_16x16x32_bf16(pa, vf, acco[nd], 0, 0, 0);
        }
      }
      __syncthreads();   // drain next-tile DMA + barrier; buf ready
      cur ^= 1;
    }

    // normalize + store O as (b, s, e) bf16
#pragma unroll
    for (int r = 0; r < 4; r++) {
      float inv = 1.0f / rs[r];
      int srow = q0 + w * 16 + lk * 4 + r;
      unsigned short* dst = ob + ((size_t)b * S_LEN + srow) * DMODEL + h * HDIM;
#pragma unroll
      for (int nd = 0; nd < 8; nd++) dst[nd * 16 + lq] = f2bf(acco[nd][r] * inv);
    }
  }
}

// ---------------- output projection GEMM (fp32 out) ----------------
__global__ __launch_bounds__(256) void k_gemm_out(
    const unsigned short* __restrict__ ob, const unsigned short* __restrict__ wob,
    const float* __restrict__ bo, float* __restrict__ out) {
  __shared__ unsigned short As[128][64];
  __shared__ unsigned short Bs[128][64];
  int m0 = blockIdx.x * 128, n0 = blockIdx.y * 128;
  int tid = threadIdx.x, lane = tid & 63, wid = tid >> 6;
  int wr = wid >> 1, wc = wid & 1;
  int lq = lane & 15, lk = lane >> 4;
  int gr = wid * 32 + (lane >> 3);
  int gc = ((lane & 7) * 8) ^ ((lane >> 3) << 3);

  f32x4 acc[4][4];
#pragma unroll
  for (int m = 0; m < 4; m++)
#pragma unroll
    for (int n = 0; n < 4; n++) { acc[m][n][0]=0.f; acc[m][n][1]=0.f; acc[m][n][2]=0.f; acc[m][n][3]=0.f; }

  for (int k0 = 0; k0 < DMODEL; k0 += 64) {
#pragma unroll
    for (int i = 0; i < 4; i++) {
      gl_lds16(ob  + (size_t)(m0 + gr + i * 8) * DMODEL + k0 + gc, &As[wid * 32 + i * 8][0]);
      gl_lds16(wob + (size_t)(n0 + gr + i * 8) * DMODEL + k0 + gc, &Bs[wid * 32 + i * 8][0]);
    }
    __syncthreads();
#pragma unroll
    for (int kk = 0; kk < 2; kk++) {
      short8 af[4], bfr[4];
      int sw = (lq & 7) << 3;
#pragma unroll
      for (int m = 0; m < 4; m++)
        af[m] = *(const short8*)&As[wr * 64 + m * 16 + lq][(kk * 32 + lk * 8) ^ sw];
#pragma unroll
      for (int n = 0; n < 4; n++)
        bfr[n] = *(const short8*)&Bs[wc * 64 + n * 16 + lq][(kk * 32 + lk * 8) ^ sw];
#pragma unroll
      for (int m = 0; m < 4; m++)
#pragma unroll
        for (int n = 0; n < 4; n++)
          acc[m][n] = __builtin_amdgcn_mfma_f32_16x16x32_bf16(af[m], bfr[n], acc[m][n], 0, 0, 0);
    }
    __syncthreads();
  }
#pragma unroll
  for (int n = 0; n < 4; n++) {
    int el = n0 + wc * 64 + n * 16 + lq;
    float bi = bo[el];
#pragma unroll
    for (int m = 0; m < 4; m++) {
      int row = m0 + wr * 64 + m * 16 + lk * 4;
#pragma unroll
      for (int r = 0; r < 4; r++)
        out[(size_t)(row + r) * DMODEL + el] = acc[m][n][r] + bi;
    }
  }
}

extern "C" void kernel_launch(void* const* d_in, const int* in_sizes, int n_in,
                              void* d_out, int out_size, void* d_ws, size_t ws_size,
                              hipStream_t stream) {
  const float* x  = (const float*)d_in[0];
  const float* Wq = (const float*)d_in[2];
  const float* bq = (const float*)d_in[3];
  const float* Wk = (const float*)d_in[4];
  const float* bk = (const float*)d_in[5];
  const float* Wv = (const float*)d_in[6];
  const float* bv = (const float*)d_in[7];
  const float* Wo = (const float*)d_in[8];
  const float* bo = (const float*)d_in[9];
  float* out = (float*)d_out;
  char* ws = (char*)d_ws;

  unsigned short* xb  = (unsigned short*)(ws + XB_OFF);
  unsigned short* wqb = (unsigned short*)(ws + WQ_OFF);
  unsigned short* wkb = (unsigned short*)(ws + WK_OFF);
  unsigned short* wvb = (unsigned short*)(ws + WV_OFF);
  unsigned short* qr  = (unsigned short*)(ws + Q_OFF);
  unsigned short* kr  = (unsigned short*)(ws + K_OFF);
  unsigned short* vt  = (unsigned short*)(ws + VT_OFF);
  float* ct = (float*)(ws + COS_OFF);
  float* st = (float*)(ws + SIN_OFF);

  k_cvt<<<(MROWS * DMODEL / 4 + 255) / 256, 256, 0, stream>>>(x, xb, MROWS * DMODEL / 4);
  k_cvtw<<<3 * 1048576 / 256, 256, 0, stream>>>(Wq, Wk, Wv, wqb, wkb, wvb);
  k_rope_table<<<(S_LEN * 64 + 255) / 256, 256, 0, stream>>>(ct, st);
  // fused QKV projection + RoPE + layout transform (Q scaled by 1/sqrt(128))
  k_gemm_qkv<<<dim3(MROWS / 128, 6144 / 128), 256, 0, stream>>>(
      xb, wqb, wkb, wvb, bq, bk, bv, ct, st, qr, kr, vt);
  k_cvt<<<(DMODEL * DMODEL / 4 + 255) / 256, 256, 0, stream>>>(Wo, wqb, DMODEL * DMODEL / 4);
  k_attn<<<dim3(BHTOT, 16), 256, 0, stream>>>(qr, kr, vt, xb);
  k_gemm_out<<<dim3(MROWS / 128, DMODEL / 128), 256, 0, stream>>>(xb, wqb, bo, out);
}

// Round 7
// 274.959 us; speedup vs baseline: 1.5836x; 1.0148x over previous
//
#include <hip/hip_runtime.h>
#include <stdint.h>
#include <math.h>

typedef short short8 __attribute__((ext_vector_type(8)));
typedef float f32x4 __attribute__((ext_vector_type(4)));

// Problem constants
#define S_LEN   2048
#define DMODEL  2048
#define NHEADS  16
#define HDIM    128
#define NBATCH  2
#define BHTOT   32      // NBATCH*NHEADS
#define MROWS   4096    // NBATCH*S_LEN

// Workspace byte offsets
#define XB_OFF   ((size_t)0)          // x bf16; reused as attn-output O
#define WQ_OFF   ((size_t)16777216)   // Wq bf16; reused for Wo bf16
#define WK_OFF   ((size_t)25165824)
#define WV_OFF   ((size_t)33554432)
#define Q_OFF    ((size_t)41943040)   // (bh,s,d) bf16
#define K_OFF    ((size_t)58720256)   // (bh,s,d) bf16
#define VT_OFF   ((size_t)75497472)   // (bh,d,s) bf16 (V pre-transposed)
#define COS_OFF  ((size_t)92274688)   // 2048*64 f32
#define SIN_OFF  ((size_t)92798976)   // 2048*64 f32

__device__ __forceinline__ unsigned short f2bf(float f) {
  unsigned int u = __float_as_uint(f);
  unsigned int r = (u + 0x7FFFu + ((u >> 16) & 1u)) >> 16;  // RTNE
  return (unsigned short)r;
}
__device__ __forceinline__ float bf2f(unsigned short b) {
  return __uint_as_float(((unsigned int)b) << 16);
}

// async global->LDS, 16B per lane; LDS dest = wave-uniform base + lane*16
__device__ __forceinline__ void gl_lds16(const unsigned short* g, unsigned short* l) {
  __builtin_amdgcn_global_load_lds(
      (const __attribute__((address_space(1))) unsigned int*)(g),
      (__attribute__((address_space(3))) unsigned int*)(l),
      16, 0, 0);
}

// ---------------- fp32 -> bf16 convert (vectorized; used for Wo) ----------------
__global__ __launch_bounds__(256) void k_cvt(const float* __restrict__ src,
                                             unsigned short* __restrict__ dst, int n4) {
  int i = blockIdx.x * 256 + threadIdx.x;
  if (i >= n4) return;
  float4 v = ((const float4*)src)[i];
  ushort4 o;
  o.x = f2bf(v.x); o.y = f2bf(v.y); o.z = f2bf(v.z); o.w = f2bf(v.w);
  ((ushort4*)dst)[i] = o;
}

// ---------------- merged prep: x->bf16, Wq/Wk/Wv->bf16, RoPE table ----------------
__global__ __launch_bounds__(256) void k_prep(
    const float* __restrict__ x, const float* __restrict__ Wq,
    const float* __restrict__ Wk, const float* __restrict__ Wv,
    unsigned short* __restrict__ xb, unsigned short* __restrict__ wqb,
    unsigned short* __restrict__ wkb, unsigned short* __restrict__ wvb,
    float* __restrict__ ct, float* __restrict__ st) {
  int i = blockIdx.x * 256 + threadIdx.x;
  if (i < 5242880) {                       // float4 converts: x (2^21) + 3 W (2^20 each)
    const float* s; unsigned short* d; int off;
    if (i < 2097152) { s = x; d = xb; off = i; }
    else {
      int j = i - 2097152, sel = j >> 20;
      off = j & 1048575;
      s = (sel == 0) ? Wq : (sel == 1 ? Wk : Wv);
      d = (sel == 0) ? wqb : (sel == 1 ? wkb : wvb);
    }
    float4 v = ((const float4*)s)[off];
    ushort4 o;
    o.x = f2bf(v.x); o.y = f2bf(v.y); o.z = f2bf(v.z); o.w = f2bf(v.w);
    ((ushort4*)d)[off] = o;
  } else {
    int j = i - 5242880;                   // 2048*64 rope table entries
    if (j < S_LEN * 64) {
      int s = j >> 6, jj = j & 63;
      float inv = expf(-(float)(2 * jj) * (9.210340371976184f / 128.0f));
      float ang = (float)s * inv;
      ct[j] = cosf(ang);
      st[j] = sinf(ang);
    }
  }
}

// ---------------- fused QKV projection GEMM + RoPE + transpose epilogue ----------------
#define CP 136
__global__ __launch_bounds__(256) void k_gemm_qkv(
    const unsigned short* __restrict__ xb,
    const unsigned short* __restrict__ wqb, const unsigned short* __restrict__ wkb,
    const unsigned short* __restrict__ wvb,
    const float* __restrict__ bq, const float* __restrict__ bk, const float* __restrict__ bv,
    const float* __restrict__ ct, const float* __restrict__ st,
    unsigned short* __restrict__ qr, unsigned short* __restrict__ kr,
    unsigned short* __restrict__ vt) {
  __shared__ unsigned short SMEM[128 * CP];
  unsigned short* As = SMEM;
  unsigned short* Bs = SMEM + 8192;
  // T1 XCD swizzle: 1536 blocks, 192/XCD; each XCD keeps 6 B-panels + rotating A in L2
  int bid = blockIdx.y * 32 + blockIdx.x;
  int nb = (bid & 7) * 192 + (bid >> 3);
  int m0 = (nb & 31) * 128;
  int n0g = (nb >> 5) * 128;               // 0..6143
  int wsel = n0g >> 11;                    // 0=Q 1=K 2=V
  int nw0 = n0g & (DMODEL - 1);
  const unsigned short* W = (wsel == 0) ? wqb : (wsel == 1 ? wkb : wvb);
  const float* bias = (wsel == 0) ? bq : (wsel == 1 ? bk : bv);
  int tid = threadIdx.x, lane = tid & 63, wid = tid >> 6;
  int wr = wid >> 1, wc = wid & 1;
  int lq = lane & 15, lk = lane >> 4;
  int gr = wid * 32 + (lane >> 3);                       // staging row (i=0)
  int gc = ((lane & 7) * 8) ^ ((lane >> 3) << 3);        // pre-swizzled source col

  f32x4 acc[4][4];
#pragma unroll
  for (int m = 0; m < 4; m++)
#pragma unroll
    for (int n = 0; n < 4; n++) { acc[m][n][0]=0.f; acc[m][n][1]=0.f; acc[m][n][2]=0.f; acc[m][n][3]=0.f; }

  for (int k0 = 0; k0 < DMODEL; k0 += 64) {
#pragma unroll
    for (int i = 0; i < 4; i++) {
      gl_lds16(xb + (size_t)(m0 + gr + i * 8) * DMODEL + k0 + gc, As + (wid * 32 + i * 8) * 64);
      gl_lds16(W  + (size_t)(nw0 + gr + i * 8) * DMODEL + k0 + gc, Bs + (wid * 32 + i * 8) * 64);
    }
    __syncthreads();
#pragma unroll
    for (int kk = 0; kk < 2; kk++) {
      short8 af[4], bfr[4];
      int sw = (lq & 7) << 3;
#pragma unroll
      for (int m = 0; m < 4; m++)
        af[m] = *(const short8*)&As[(wr * 64 + m * 16 + lq) * 64 + ((kk * 32 + lk * 8) ^ sw)];
#pragma unroll
      for (int n = 0; n < 4; n++)
        bfr[n] = *(const short8*)&Bs[(wc * 64 + n * 16 + lq) * 64 + ((kk * 32 + lk * 8) ^ sw)];
#pragma unroll
      for (int m = 0; m < 4; m++)
#pragma unroll
        for (int n = 0; n < 4; n++)
          acc[m][n] = __builtin_amdgcn_mfma_f32_16x16x32_bf16(af[m], bfr[n], acc[m][n], 0, 0, 0);
    }
    __syncthreads();
  }

  // ---- epilogue: bias (+RoPE for Q/K) -> SMEM in target layout -> coalesced store
  int h = nw0 >> 7, b = m0 >> 11, s0 = m0 & (S_LEN - 1);
  float bi[4];
#pragma unroll
  for (int n = 0; n < 4; n++) bi[n] = bias[nw0 + wc * 64 + n * 16 + lq];

  if (wsel < 2) {
    float qs = (wsel == 0) ? 0.08838834764831843f : 1.0f;
    if (wc == 0) {
#pragma unroll
      for (int m = 0; m < 4; m++) {
        int sl = wr * 64 + m * 16 + lk * 4;
#pragma unroll
        for (int r = 0; r < 4; r++) {
          int s = (s0 + sl + r);
          const float* cb = ct + s * 64;
          const float* sb = st + s * 64;
#pragma unroll
          for (int n = 0; n < 2; n++) {
            int fq = n * 16 + lq;
            float x1 = acc[m][n][r] + bi[n];
            float x2 = acc[m][n + 2][r] + bi[n + 2];
            SMEM[(sl + r) * CP + fq]      = f2bf((x1 * cb[fq]      - x2 * sb[fq])      * qs);
            SMEM[(sl + r) * CP + fq + 32] = f2bf((x2 * cb[fq + 32] + x1 * sb[fq + 32]) * qs);
          }
        }
      }
    } else {
#pragma unroll
      for (int m = 0; m < 4; m++) {
        int sl = wr * 64 + m * 16 + lk * 4;
#pragma unroll
        for (int n = 0; n < 4; n++) {
          int fq = 64 + n * 16 + lq;
#pragma unroll
          for (int r = 0; r < 4; r++)
            SMEM[(sl + r) * CP + fq] = f2bf((acc[m][n][r] + bi[n]) * qs);
        }
      }
    }
    __syncthreads();
    int row = tid >> 1, hf2 = tid & 1;
    unsigned short* dstb = (wsel == 0 ? qr : kr) +
        ((size_t)(b * NHEADS + h) * S_LEN + s0 + row) * HDIM + hf2 * 64;
    const unsigned short* srcb = &SMEM[row * CP + hf2 * 64];
#pragma unroll
    for (int j = 0; j < 8; j++)
      *(short8*)(dstb + j * 8) = *(const short8*)(srcb + j * 8);
  } else {
#pragma unroll
    for (int m = 0; m < 4; m++) {
      int sl = wr * 64 + m * 16 + lk * 4;
#pragma unroll
      for (int n = 0; n < 4; n++) {
        int fq = wc * 64 + n * 16 + lq;
#pragma unroll
        for (int r = 0; r < 4; r++)
          SMEM[fq * CP + sl + r] = f2bf(acc[m][n][r] + bi[n]);
      }
    }
    __syncthreads();
    int row = tid >> 1, hf2 = tid & 1;
    unsigned short* dstb = vt +
        ((size_t)(b * NHEADS + h) * HDIM + row) * S_LEN + s0 + hf2 * 64;
    const unsigned short* srcb = &SMEM[row * CP + hf2 * 64];
#pragma unroll
    for (int j = 0; j < 8; j++)
      *(short8*)(dstb + j * 8) = *(const short8*)(srcb + j * 8);
  }
}

// ---------------- attn per-tile softmax (defer-max) + P->LDS + PV ----------------
__device__ __forceinline__ void attn_sm_pv(
    f32x4* sacc, f32x4* acco, float* rm, float* rs,
    unsigned short (*Psw)[72], const unsigned short* V0,
    int lq, int lk, int rsw) {
  float mx4[4];
  int need = 0;
#pragma unroll
  for (int r = 0; r < 4; r++) {
    float mx = fmaxf(fmaxf(sacc[0][r], sacc[1][r]), fmaxf(sacc[2][r], sacc[3][r]));
    mx = fmaxf(mx, __shfl_xor(mx, 1, 64));
    mx = fmaxf(mx, __shfl_xor(mx, 2, 64));
    mx = fmaxf(mx, __shfl_xor(mx, 4, 64));
    mx = fmaxf(mx, __shfl_xor(mx, 8, 64));
    mx4[r] = mx;
    need |= (mx - rm[r] > 8.0f) ? 1 : 0;
  }
  if (__any(need)) {
#pragma unroll
    for (int r = 0; r < 4; r++) {
      float mnew = fmaxf(rm[r], mx4[r]);
      float corr = __expf(rm[r] - mnew);
      rs[r] *= corr;
#pragma unroll
      for (int nd = 0; nd < 8; nd++) acco[nd][r] *= corr;
      rm[r] = mnew;
    }
  }
#pragma unroll
  for (int r = 0; r < 4; r++) {
    float psum = 0.f;
#pragma unroll
    for (int n = 0; n < 4; n++) {
      float p = __expf(sacc[n][r] - rm[r]);
      sacc[n][r] = p;
      psum += p;
    }
    psum += __shfl_xor(psum, 1, 64);
    psum += __shfl_xor(psum, 2, 64);
    psum += __shfl_xor(psum, 4, 64);
    psum += __shfl_xor(psum, 8, 64);
    rs[r] += psum;
  }
#pragma unroll
  for (int n = 0; n < 4; n++)
#pragma unroll
    for (int r = 0; r < 4; r++)
      Psw[lk * 4 + r][n * 16 + lq] = f2bf(sacc[n][r]);
#pragma unroll
  for (int ks2 = 0; ks2 < 2; ks2++) {
    short8 pa = *(const short8*)&Psw[lq][ks2 * 32 + lk * 8];
#pragma unroll
    for (int nd = 0; nd < 8; nd++) {
      short8 vf = *(const short8*)&V0[(nd * 16 + lq) * 64 + ((ks2 * 32 + lk * 8) ^ rsw)];
      acco[nd] = __builtin_amdgcn_mfma_f32_16x16x32_bf16(pa, vf, acco[nd], 0, 0, 0);
    }
  }
}

// ---------------- causal flash attention (merged dual-q-tile sweep) ----------------
// Block owns q-tiles {31-f, f}; ONE KV sweep t=0..31-f serves both (tile B active
// while t<=f). K-frag ds_reads shared by both QK^T; staging/barriers -26%;
// overlap steps give 2 independent chains of ILP. y->f map pairs long+short
// blocks on the same CU (i and i+256).
__global__ __launch_bounds__(256, 2) void k_attn(
    const unsigned short* __restrict__ qr, const unsigned short* __restrict__ kr,
    const unsigned short* __restrict__ vt, unsigned short* __restrict__ ob) {
  __shared__ unsigned short Kl[2][64 * 128];   // [kv][d] swizzled flat, dbuf
  __shared__ unsigned short Vl[2][128 * 64];   // [d][kv] swizzled flat, dbuf
  __shared__ unsigned short Ps[4][16][72];     // per-wave P round-trip
  int bh = blockIdx.x;
  int yy = blockIdx.y;
  int f = (yy < 8) ? yy : 23 - yy;             // bijective over 0..15
  int qtA = 31 - f, qtB = f;
  int q0A = qtA * 64, q0B = qtB * 64;
  int b = bh >> 4, h = bh & 15;
  int tid = threadIdx.x, lane = tid & 63, w = tid >> 6;
  int lq = lane & 15, lk = lane >> 4;
  const unsigned short* kbh = kr + (size_t)bh * S_LEN * HDIM;
  const unsigned short* vbh = vt + (size_t)bh * HDIM * S_LEN;
  int ksrow = tid >> 4;
  int kscol = ((tid & 15) * 8) ^ ((ksrow & 7) << 3);
  int vsrow = tid >> 3;
  int vscol = ((tid & 7) * 8) ^ ((vsrow & 7) << 3);
  int ldso = tid * 8;
  int rsw = (lq & 7) << 3;

  const unsigned short* qbA =
      qr + ((size_t)bh * S_LEN + q0A + w * 16 + lq) * HDIM + lk * 8;
  const unsigned short* qbB =
      qr + ((size_t)bh * S_LEN + q0B + w * 16 + lq) * HDIM + lk * 8;
  short8 qfA[4], qfB[4];
#pragma unroll
  for (int ks = 0; ks < 4; ks++) {
    qfA[ks] = *(const short8*)(qbA + ks * 32);
    qfB[ks] = *(const short8*)(qbB + ks * 32);
  }

  f32x4 accoA[8], accoB[8];
#pragma unroll
  for (int nd = 0; nd < 8; nd++) {
    accoA[nd][0]=0.f; accoA[nd][1]=0.f; accoA[nd][2]=0.f; accoA[nd][3]=0.f;
    accoB[nd][0]=0.f; accoB[nd][1]=0.f; accoB[nd][2]=0.f; accoB[nd][3]=0.f;
  }
  float rmA[4], rsA[4], rmB[4], rsB[4];
#pragma unroll
  for (int r = 0; r < 4; r++) { rmA[r] = -3.0e38f; rsA[r] = 0.f; rmB[r] = -3.0e38f; rsB[r] = 0.f; }

  // prologue: stage tile 0 into buf 0
#pragma unroll
  for (int c = 0; c < 4; c++) {
    gl_lds16(kbh + (size_t)(c * 16 + ksrow) * HDIM + kscol, &Kl[0][c * 2048 + ldso]);
    gl_lds16(vbh + (size_t)(c * 32 + vsrow) * S_LEN + vscol, &Vl[0][c * 2048 + ldso]);
  }
  __syncthreads();
  int cur = 0;

  for (int t = 0; t <= qtA; t++) {
    int kv0 = t * 64;
    if (t < qtA) {
      int nx = kv0 + 64;
#pragma unroll
      for (int c = 0; c < 4; c++) {
        gl_lds16(kbh + (size_t)(nx + c * 16 + ksrow) * HDIM + kscol,
                 &Kl[cur ^ 1][c * 2048 + ldso]);
        gl_lds16(vbh + (size_t)(c * 32 + vsrow) * S_LEN + nx + vscol,
                 &Vl[cur ^ 1][c * 2048 + ldso]);
      }
    }
    const unsigned short* K0 = &Kl[cur][0];
    const unsigned short* V0 = &Vl[cur][0];
    bool actB = (t <= qtB);

    f32x4 saccA[4], saccB[4];
#pragma unroll
    for (int n = 0; n < 4; n++) {
      saccA[n][0]=0.f; saccA[n][1]=0.f; saccA[n][2]=0.f; saccA[n][3]=0.f;
      saccB[n][0]=0.f; saccB[n][1]=0.f; saccB[n][2]=0.f; saccB[n][3]=0.f;
    }
    if (actB) {
#pragma unroll
      for (int ks = 0; ks < 4; ks++)
#pragma unroll
        for (int n = 0; n < 4; n++) {
          short8 kf = *(const short8*)&K0[(n * 16 + lq) * 128 + ((ks * 32 + lk * 8) ^ rsw)];
          saccA[n] = __builtin_amdgcn_mfma_f32_16x16x32_bf16(qfA[ks], kf, saccA[n], 0, 0, 0);
          saccB[n] = __builtin_amdgcn_mfma_f32_16x16x32_bf16(qfB[ks], kf, saccB[n], 0, 0, 0);
        }
    } else {
#pragma unroll
      for (int ks = 0; ks < 4; ks++)
#pragma unroll
        for (int n = 0; n < 4; n++) {
          short8 kf = *(const short8*)&K0[(n * 16 + lq) * 128 + ((ks * 32 + lk * 8) ^ rsw)];
          saccA[n] = __builtin_amdgcn_mfma_f32_16x16x32_bf16(qfA[ks], kf, saccA[n], 0, 0, 0);
        }
    }
    if (t == qtA) {
#pragma unroll
      for (int n = 0; n < 4; n++)
#pragma unroll
        for (int r = 0; r < 4; r++) {
          int qrow = q0A + w * 16 + lk * 4 + r;
          int kvc = kv0 + n * 16 + lq;
          if (kvc > qrow) saccA[n][r] = -3.0e38f;
        }
    }
    attn_sm_pv(saccA, accoA, rmA, rsA, Ps[w], V0, lq, lk, rsw);
    if (actB) {
      if (t == qtB) {
#pragma unroll
        for (int n = 0; n < 4; n++)
#pragma unroll
          for (int r = 0; r < 4; r++) {
            int qrow = q0B + w * 16 + lk * 4 + r;
            int kvc = kv0 + n * 16 + lq;
            if (kvc > qrow) saccB[n][r] = -3.0e38f;
          }
      }
      attn_sm_pv(saccB, accoB, rmB, rsB, Ps[w], V0, lq, lk, rsw);
    }
    __syncthreads();   // drain next-tile DMA + barrier; buf ready
    cur ^= 1;
  }

  // normalize + store O as (b, s, e) bf16 for both tiles
#pragma unroll
  for (int r = 0; r < 4; r++) {
    float invA = 1.0f / rsA[r];
    int srowA = q0A + w * 16 + lk * 4 + r;
    unsigned short* dstA = ob + ((size_t)b * S_LEN + srowA) * DMODEL + h * HDIM;
#pragma unroll
    for (int nd = 0; nd < 8; nd++) dstA[nd * 16 + lq] = f2bf(accoA[nd][r] * invA);
    float invB = 1.0f / rsB[r];
    int srowB = q0B + w * 16 + lk * 4 + r;
    unsigned short* dstB = ob + ((size_t)b * S_LEN + srowB) * DMODEL + h * HDIM;
#pragma unroll
    for (int nd = 0; nd < 8; nd++) dstB[nd * 16 + lq] = f2bf(accoB[nd][r] * invB);
  }
}

// ---------------- output projection GEMM (fp32 out) ----------------
__global__ __launch_bounds__(256) void k_gemm_out(
    const unsigned short* __restrict__ ob, const unsigned short* __restrict__ wob,
    const float* __restrict__ bo, float* __restrict__ out) {
  __shared__ unsigned short As[128][64];
  __shared__ unsigned short Bs[128][64];
  int bid = blockIdx.y * 32 + blockIdx.x;   // grid (32,16) -> 512
  int nb = (bid & 7) * 64 + (bid >> 3);     // T1 XCD swizzle
  int m0 = (nb & 31) * 128;
  int n0 = (nb >> 5) * 128;
  int tid = threadIdx.x, lane = tid & 63, wid = tid >> 6;
  int wr = wid >> 1, wc = wid & 1;
  int lq = lane & 15, lk = lane >> 4;
  int gr = wid * 32 + (lane >> 3);
  int gc = ((lane & 7) * 8) ^ ((lane >> 3) << 3);

  f32x4 acc[4][4];
#pragma unroll
  for (int m = 0; m < 4; m++)
#pragma unroll
    for (int n = 0; n < 4; n++) { acc[m][n][0]=0.f; acc[m][n][1]=0.f; acc[m][n][2]=0.f; acc[m][n][3]=0.f; }

  for (int k0 = 0; k0 < DMODEL; k0 += 64) {
#pragma unroll
    for (int i = 0; i < 4; i++) {
      gl_lds16(ob  + (size_t)(m0 + gr + i * 8) * DMODEL + k0 + gc, &As[wid * 32 + i * 8][0]);
      gl_lds16(wob + (size_t)(n0 + gr + i * 8) * DMODEL + k0 + gc, &Bs[wid * 32 + i * 8][0]);
    }
    __syncthreads();
#pragma unroll
    for (int kk = 0; kk < 2; kk++) {
      short8 af[4], bfr[4];
      int sw = (lq & 7) << 3;
#pragma unroll
      for (int m = 0; m < 4; m++)
        af[m] = *(const short8*)&As[wr * 64 + m * 16 + lq][(kk * 32 + lk * 8) ^ sw];
#pragma unroll
      for (int n = 0; n < 4; n++)
        bfr[n] = *(const short8*)&Bs[wc * 64 + n * 16 + lq][(kk * 32 + lk * 8) ^ sw];
#pragma unroll
      for (int m = 0; m < 4; m++)
#pragma unroll
        for (int n = 0; n < 4; n++)
          acc[m][n] = __builtin_amdgcn_mfma_f32_16x16x32_bf16(af[m], bfr[n], acc[m][n], 0, 0, 0);
    }
    __syncthreads();
  }
#pragma unroll
  for (int n = 0; n < 4; n++) {
    int el = n0 + wc * 64 + n * 16 + lq;
    float bi = bo[el];
#pragma unroll
    for (int m = 0; m < 4; m++) {
      int row = m0 + wr * 64 + m * 16 + lk * 4;
#pragma unroll
      for (int r = 0; r < 4; r++)
        out[(size_t)(row + r) * DMODEL + el] = acc[m][n][r] + bi;
    }
  }
}

extern "C" void kernel_launch(void* const* d_in, const int* in_sizes, int n_in,
                              void* d_out, int out_size, void* d_ws, size_t ws_size,
                              hipStream_t stream) {
  const float* x  = (const float*)d_in[0];
  const float* Wq = (const float*)d_in[2];
  const float* bq = (const float*)d_in[3];
  const float* Wk = (const float*)d_in[4];
  const float* bk = (const float*)d_in[5];
  const float* Wv = (const float*)d_in[6];
  const float* bv = (const float*)d_in[7];
  const float* Wo = (const float*)d_in[8];
  const float* bo = (const float*)d_in[9];
  float* out = (float*)d_out;
  char* ws = (char*)d_ws;

  unsigned short* xb  = (unsigned short*)(ws + XB_OFF);
  unsigned short* wqb = (unsigned short*)(ws + WQ_OFF);
  unsigned short* wkb = (unsigned short*)(ws + WK_OFF);
  unsigned short* wvb = (unsigned short*)(ws + WV_OFF);
  unsigned short* qr  = (unsigned short*)(ws + Q_OFF);
  unsigned short* kr  = (unsigned short*)(ws + K_OFF);
  unsigned short* vt  = (unsigned short*)(ws + VT_OFF);
  float* ct = (float*)(ws + COS_OFF);
  float* st = (float*)(ws + SIN_OFF);

  // x + Wq/Wk/Wv converts + rope table, one launch
  k_prep<<<20992, 256, 0, stream>>>(x, Wq, Wk, Wv, xb, wqb, wkb, wvb, ct, st);
  // fused QKV projection + RoPE + layout transform (Q scaled by 1/sqrt(128))
  k_gemm_qkv<<<dim3(MROWS / 128, 6144 / 128), 256, 0, stream>>>(
      xb, wqb, wkb, wvb, bq, bk, bv, ct, st, qr, kr, vt);
  k_cvt<<<(DMODEL * DMODEL / 4 + 255) / 256, 256, 0, stream>>>(Wo, wqb, DMODEL * DMODEL / 4);
  k_attn<<<dim3(BHTOT, 16), 256, 0, stream>>>(qr, kr, vt, xb);
  k_gemm_out<<<dim3(MROWS / 128, DMODEL / 128), 256, 0, stream>>>(xb, wqb, bo, out);
}

// Round 8
// 259.286 us; speedup vs baseline: 1.6793x; 1.0604x over previous
//
#include <hip/hip_runtime.h>
#include <stdint.h>
#include <math.h>

typedef short short8 __attribute__((ext_vector_type(8)));
typedef float f32x4 __attribute__((ext_vector_type(4)));

// Problem constants
#define S_LEN   2048
#define DMODEL  2048
#define NHEADS  16
#define HDIM    128
#define NBATCH  2
#define BHTOT   32      // NBATCH*NHEADS
#define MROWS   4096    // NBATCH*S_LEN

// Workspace byte offsets
#define XB_OFF   ((size_t)0)          // x bf16; reused as attn-output O
#define WQ_OFF   ((size_t)16777216)   // Wq bf16; reused for Wo bf16 (fallback path)
#define WK_OFF   ((size_t)25165824)
#define WV_OFF   ((size_t)33554432)
#define Q_OFF    ((size_t)41943040)   // (bh,s,d) bf16
#define K_OFF    ((size_t)58720256)   // (bh,s,d) bf16
#define VT_OFF   ((size_t)75497472)   // (bh,d,s) bf16 (V pre-transposed)
#define COS_OFF  ((size_t)92274688)   // 2048*64 f32
#define SIN_OFF  ((size_t)92798976)   // 2048*64 f32
#define WO_OFF   ((size_t)93323264)   // dedicated Wo bf16 slot (if ws_size permits)
#define WS_NEED  (WO_OFF + (size_t)8388608)

__device__ __forceinline__ unsigned short f2bf(float f) {
  unsigned int u = __float_as_uint(f);
  unsigned int r = (u + 0x7FFFu + ((u >> 16) & 1u)) >> 16;  // RTNE
  return (unsigned short)r;
}
__device__ __forceinline__ float bf2f(unsigned short b) {
  return __uint_as_float(((unsigned int)b) << 16);
}

// async global->LDS, 16B per lane; LDS dest = wave-uniform base + lane*16
__device__ __forceinline__ void gl_lds16(const unsigned short* g, unsigned short* l) {
  __builtin_amdgcn_global_load_lds(
      (const __attribute__((address_space(1))) unsigned int*)(g),
      (__attribute__((address_space(3))) unsigned int*)(l),
      16, 0, 0);
}

// ---------------- fp32 -> bf16 convert (fallback for Wo) ----------------
__global__ __launch_bounds__(256) void k_cvt(const float* __restrict__ src,
                                             unsigned short* __restrict__ dst, int n4) {
  int i = blockIdx.x * 256 + threadIdx.x;
  if (i >= n4) return;
  float4 v = ((const float4*)src)[i];
  ushort4 o;
  o.x = f2bf(v.x); o.y = f2bf(v.y); o.z = f2bf(v.z); o.w = f2bf(v.w);
  ((ushort4*)dst)[i] = o;
}

// ---------------- merged prep: x->bf16, Wq/Wk/Wv(/Wo)->bf16, RoPE table ----------------
__global__ __launch_bounds__(256) void k_prep(
    const float* __restrict__ x, const float* __restrict__ Wq,
    const float* __restrict__ Wk, const float* __restrict__ Wv,
    const float* __restrict__ Wo,
    unsigned short* __restrict__ xb, unsigned short* __restrict__ wqb,
    unsigned short* __restrict__ wkb, unsigned short* __restrict__ wvb,
    unsigned short* __restrict__ wob,   // null if no dedicated slot
    float* __restrict__ ct, float* __restrict__ st) {
  int i = blockIdx.x * 256 + threadIdx.x;
  if (i < 6291456) {                       // float4 converts: x (2^21) + 4 W (2^20 each)
    const float* s; unsigned short* d; int off;
    if (i < 2097152) { s = x; d = xb; off = i; }
    else {
      int j = i - 2097152, sel = j >> 20;
      off = j & 1048575;
      if (sel == 3) {
        if (!wob) return;                  // fallback: separate k_cvt handles Wo
        s = Wo; d = wob;
      } else {
        s = (sel == 0) ? Wq : (sel == 1 ? Wk : Wv);
        d = (sel == 0) ? wqb : (sel == 1 ? wkb : wvb);
      }
    }
    float4 v = ((const float4*)s)[off];
    ushort4 o;
    o.x = f2bf(v.x); o.y = f2bf(v.y); o.z = f2bf(v.z); o.w = f2bf(v.w);
    ((ushort4*)d)[off] = o;
  } else {
    int j = i - 6291456;                   // 2048*64 rope table entries
    if (j < S_LEN * 64) {
      int s = j >> 6, jj = j & 63;
      float inv = expf(-(float)(2 * jj) * (9.210340371976184f / 128.0f));
      float ang = (float)s * inv;
      ct[j] = cosf(ang);
      st[j] = sinf(ang);
    }
  }
}

// ---------------- fused QKV projection GEMM + RoPE + transpose epilogue ----------------
#define CP 136
__global__ __launch_bounds__(256) void k_gemm_qkv(
    const unsigned short* __restrict__ xb,
    const unsigned short* __restrict__ wqb, const unsigned short* __restrict__ wkb,
    const unsigned short* __restrict__ wvb,
    const float* __restrict__ bq, const float* __restrict__ bk, const float* __restrict__ bv,
    const float* __restrict__ ct, const float* __restrict__ st,
    unsigned short* __restrict__ qr, unsigned short* __restrict__ kr,
    unsigned short* __restrict__ vt) {
  __shared__ unsigned short SMEM[128 * CP];
  unsigned short* As = SMEM;
  unsigned short* Bs = SMEM + 8192;
  int m0 = blockIdx.x * 128;               // plain mapping (r7 swizzle: FETCH +75%, dur flat)
  int n0g = blockIdx.y * 128;              // 0..6143
  int wsel = n0g >> 11;                    // 0=Q 1=K 2=V
  int nw0 = n0g & (DMODEL - 1);
  const unsigned short* W = (wsel == 0) ? wqb : (wsel == 1 ? wkb : wvb);
  const float* bias = (wsel == 0) ? bq : (wsel == 1 ? bk : bv);
  int tid = threadIdx.x, lane = tid & 63, wid = tid >> 6;
  int wr = wid >> 1, wc = wid & 1;
  int lq = lane & 15, lk = lane >> 4;
  int gr = wid * 32 + (lane >> 3);                       // staging row (i=0)
  int gc = ((lane & 7) * 8) ^ ((lane >> 3) << 3);        // pre-swizzled source col

  f32x4 acc[4][4];
#pragma unroll
  for (int m = 0; m < 4; m++)
#pragma unroll
    for (int n = 0; n < 4; n++) { acc[m][n][0]=0.f; acc[m][n][1]=0.f; acc[m][n][2]=0.f; acc[m][n][3]=0.f; }

  for (int k0 = 0; k0 < DMODEL; k0 += 64) {
#pragma unroll
    for (int i = 0; i < 4; i++) {
      gl_lds16(xb + (size_t)(m0 + gr + i * 8) * DMODEL + k0 + gc, As + (wid * 32 + i * 8) * 64);
      gl_lds16(W  + (size_t)(nw0 + gr + i * 8) * DMODEL + k0 + gc, Bs + (wid * 32 + i * 8) * 64);
    }
    __syncthreads();
#pragma unroll
    for (int kk = 0; kk < 2; kk++) {
      short8 af[4], bfr[4];
      int sw = (lq & 7) << 3;
#pragma unroll
      for (int m = 0; m < 4; m++)
        af[m] = *(const short8*)&As[(wr * 64 + m * 16 + lq) * 64 + ((kk * 32 + lk * 8) ^ sw)];
#pragma unroll
      for (int n = 0; n < 4; n++)
        bfr[n] = *(const short8*)&Bs[(wc * 64 + n * 16 + lq) * 64 + ((kk * 32 + lk * 8) ^ sw)];
#pragma unroll
      for (int m = 0; m < 4; m++)
#pragma unroll
        for (int n = 0; n < 4; n++)
          acc[m][n] = __builtin_amdgcn_mfma_f32_16x16x32_bf16(af[m], bfr[n], acc[m][n], 0, 0, 0);
    }
    __syncthreads();
  }

  // ---- epilogue: bias (+RoPE for Q/K) -> SMEM in target layout -> coalesced store
  int h = nw0 >> 7, b = m0 >> 11, s0 = m0 & (S_LEN - 1);
  float bi[4];
#pragma unroll
  for (int n = 0; n < 4; n++) bi[n] = bias[nw0 + wc * 64 + n * 16 + lq];

  if (wsel < 2) {
    float qs = (wsel == 0) ? 0.08838834764831843f : 1.0f;
    if (wc == 0) {
#pragma unroll
      for (int m = 0; m < 4; m++) {
        int sl = wr * 64 + m * 16 + lk * 4;
#pragma unroll
        for (int r = 0; r < 4; r++) {
          int s = (s0 + sl + r);
          const float* cb = ct + s * 64;
          const float* sb = st + s * 64;
#pragma unroll
          for (int n = 0; n < 2; n++) {
            int fq = n * 16 + lq;
            float x1 = acc[m][n][r] + bi[n];
            float x2 = acc[m][n + 2][r] + bi[n + 2];
            SMEM[(sl + r) * CP + fq]      = f2bf((x1 * cb[fq]      - x2 * sb[fq])      * qs);
            SMEM[(sl + r) * CP + fq + 32] = f2bf((x2 * cb[fq + 32] + x1 * sb[fq + 32]) * qs);
          }
        }
      }
    } else {
#pragma unroll
      for (int m = 0; m < 4; m++) {
        int sl = wr * 64 + m * 16 + lk * 4;
#pragma unroll
        for (int n = 0; n < 4; n++) {
          int fq = 64 + n * 16 + lq;
#pragma unroll
          for (int r = 0; r < 4; r++)
            SMEM[(sl + r) * CP + fq] = f2bf((acc[m][n][r] + bi[n]) * qs);
        }
      }
    }
    __syncthreads();
    int row = tid >> 1, hf2 = tid & 1;
    unsigned short* dstb = (wsel == 0 ? qr : kr) +
        ((size_t)(b * NHEADS + h) * S_LEN + s0 + row) * HDIM + hf2 * 64;
    const unsigned short* srcb = &SMEM[row * CP + hf2 * 64];
#pragma unroll
    for (int j = 0; j < 8; j++)
      *(short8*)(dstb + j * 8) = *(const short8*)(srcb + j * 8);
  } else {
#pragma unroll
    for (int m = 0; m < 4; m++) {
      int sl = wr * 64 + m * 16 + lk * 4;
#pragma unroll
      for (int n = 0; n < 4; n++) {
        int fq = wc * 64 + n * 16 + lq;
#pragma unroll
        for (int r = 0; r < 4; r++)
          SMEM[fq * CP + sl + r] = f2bf(acc[m][n][r] + bi[n]);
      }
    }
    __syncthreads();
    int row = tid >> 1, hf2 = tid & 1;
    unsigned short* dstb = vt +
        ((size_t)(b * NHEADS + h) * HDIM + row) * S_LEN + s0 + hf2 * 64;
    const unsigned short* srcb = &SMEM[row * CP + hf2 * 64];
#pragma unroll
    for (int j = 0; j < 8; j++)
      *(short8*)(dstb + j * 8) = *(const short8*)(srcb + j * 8);
  }
}

// ---------------- attn per-tile softmax (defer-max, per-lane partial sums) ----------------
// rs[] accumulates PER-LANE partial sums; cross-lane reduce deferred to the end
// (corr rescales are lane-uniform -> partials stay consistent).
__device__ __forceinline__ void attn_sm_pv(
    f32x4* sacc, f32x4* acco, float* rm, float* rs,
    unsigned short (*Psw)[72], const unsigned short* V0,
    int lq, int lk, int rsw) {
  float mx4[4];
  int need = 0;
#pragma unroll
  for (int r = 0; r < 4; r++) {
    float mx = fmaxf(fmaxf(sacc[0][r], sacc[1][r]), fmaxf(sacc[2][r], sacc[3][r]));
    mx = fmaxf(mx, __shfl_xor(mx, 1, 64));
    mx = fmaxf(mx, __shfl_xor(mx, 2, 64));
    mx = fmaxf(mx, __shfl_xor(mx, 4, 64));
    mx = fmaxf(mx, __shfl_xor(mx, 8, 64));
    mx4[r] = mx;
    need |= (mx - rm[r] > 8.0f) ? 1 : 0;
  }
  if (__any(need)) {
#pragma unroll
    for (int r = 0; r < 4; r++) {
      float mnew = fmaxf(rm[r], mx4[r]);
      float corr = __expf(rm[r] - mnew);
      rs[r] *= corr;
#pragma unroll
      for (int nd = 0; nd < 8; nd++) acco[nd][r] *= corr;
      rm[r] = mnew;
    }
  }
#pragma unroll
  for (int r = 0; r < 4; r++) {
    float psum = 0.f;
#pragma unroll
    for (int n = 0; n < 4; n++) {
      float p = __expf(sacc[n][r] - rm[r]);
      sacc[n][r] = p;
      psum += p;
    }
    rs[r] += psum;                         // per-lane partial; no shuffles here
  }
#pragma unroll
  for (int n = 0; n < 4; n++)
#pragma unroll
    for (int r = 0; r < 4; r++)
      Psw[lk * 4 + r][n * 16 + lq] = f2bf(sacc[n][r]);
#pragma unroll
  for (int ks2 = 0; ks2 < 2; ks2++) {
    short8 pa = *(const short8*)&Psw[lq][ks2 * 32 + lk * 8];
#pragma unroll
    for (int nd = 0; nd < 8; nd++) {
      short8 vf = *(const short8*)&V0[(nd * 16 + lq) * 64 + ((ks2 * 32 + lk * 8) ^ rsw)];
      acco[nd] = __builtin_amdgcn_mfma_f32_16x16x32_bf16(pa, vf, acco[nd], 0, 0, 0);
    }
  }
}

// ---------------- causal flash attention (merged dual-q-tile sweep) ----------------
__global__ __launch_bounds__(256, 2) void k_attn(
    const unsigned short* __restrict__ qr, const unsigned short* __restrict__ kr,
    const unsigned short* __restrict__ vt, unsigned short* __restrict__ ob) {
  __shared__ unsigned short Kl[2][64 * 128];   // [kv][d] swizzled flat, dbuf
  __shared__ unsigned short Vl[2][128 * 64];   // [d][kv] swizzled flat, dbuf
  __shared__ unsigned short Ps[4][16][72];     // per-wave P round-trip
  int bh = blockIdx.x;
  int yy = blockIdx.y;
  int f = (yy < 8) ? yy : 23 - yy;             // bijective over 0..15
  int qtA = 31 - f, qtB = f;
  int q0A = qtA * 64, q0B = qtB * 64;
  int b = bh >> 4, h = bh & 15;
  int tid = threadIdx.x, lane = tid & 63, w = tid >> 6;
  int lq = lane & 15, lk = lane >> 4;
  const unsigned short* kbh = kr + (size_t)bh * S_LEN * HDIM;
  const unsigned short* vbh = vt + (size_t)bh * HDIM * S_LEN;
  int ksrow = tid >> 4;
  int kscol = ((tid & 15) * 8) ^ ((ksrow & 7) << 3);
  int vsrow = tid >> 3;
  int vscol = ((tid & 7) * 8) ^ ((vsrow & 7) << 3);
  int ldso = tid * 8;
  int rsw = (lq & 7) << 3;

  const unsigned short* qbA =
      qr + ((size_t)bh * S_LEN + q0A + w * 16 + lq) * HDIM + lk * 8;
  const unsigned short* qbB =
      qr + ((size_t)bh * S_LEN + q0B + w * 16 + lq) * HDIM + lk * 8;
  short8 qfA[4], qfB[4];
#pragma unroll
  for (int ks = 0; ks < 4; ks++) {
    qfA[ks] = *(const short8*)(qbA + ks * 32);
    qfB[ks] = *(const short8*)(qbB + ks * 32);
  }

  f32x4 accoA[8], accoB[8];
#pragma unroll
  for (int nd = 0; nd < 8; nd++) {
    accoA[nd][0]=0.f; accoA[nd][1]=0.f; accoA[nd][2]=0.f; accoA[nd][3]=0.f;
    accoB[nd][0]=0.f; accoB[nd][1]=0.f; accoB[nd][2]=0.f; accoB[nd][3]=0.f;
  }
  float rmA[4], rsA[4], rmB[4], rsB[4];
#pragma unroll
  for (int r = 0; r < 4; r++) { rmA[r] = -3.0e38f; rsA[r] = 0.f; rmB[r] = -3.0e38f; rsB[r] = 0.f; }

  // prologue: stage tile 0 into buf 0
#pragma unroll
  for (int c = 0; c < 4; c++) {
    gl_lds16(kbh + (size_t)(c * 16 + ksrow) * HDIM + kscol, &Kl[0][c * 2048 + ldso]);
    gl_lds16(vbh + (size_t)(c * 32 + vsrow) * S_LEN + vscol, &Vl[0][c * 2048 + ldso]);
  }
  __syncthreads();
  int cur = 0;

  for (int t = 0; t <= qtA; t++) {
    int kv0 = t * 64;
    if (t < qtA) {
      int nx = kv0 + 64;
#pragma unroll
      for (int c = 0; c < 4; c++) {
        gl_lds16(kbh + (size_t)(nx + c * 16 + ksrow) * HDIM + kscol,
                 &Kl[cur ^ 1][c * 2048 + ldso]);
        gl_lds16(vbh + (size_t)(c * 32 + vsrow) * S_LEN + nx + vscol,
                 &Vl[cur ^ 1][c * 2048 + ldso]);
      }
    }
    const unsigned short* K0 = &Kl[cur][0];
    const unsigned short* V0 = &Vl[cur][0];
    bool actB = (t <= qtB);

    f32x4 saccA[4], saccB[4];
#pragma unroll
    for (int n = 0; n < 4; n++) {
      saccA[n][0]=0.f; saccA[n][1]=0.f; saccA[n][2]=0.f; saccA[n][3]=0.f;
      saccB[n][0]=0.f; saccB[n][1]=0.f; saccB[n][2]=0.f; saccB[n][3]=0.f;
    }
    if (actB) {
#pragma unroll
      for (int ks = 0; ks < 4; ks++)
#pragma unroll
        for (int n = 0; n < 4; n++) {
          short8 kf = *(const short8*)&K0[(n * 16 + lq) * 128 + ((ks * 32 + lk * 8) ^ rsw)];
          saccA[n] = __builtin_amdgcn_mfma_f32_16x16x32_bf16(qfA[ks], kf, saccA[n], 0, 0, 0);
          saccB[n] = __builtin_amdgcn_mfma_f32_16x16x32_bf16(qfB[ks], kf, saccB[n], 0, 0, 0);
        }
    } else {
#pragma unroll
      for (int ks = 0; ks < 4; ks++)
#pragma unroll
        for (int n = 0; n < 4; n++) {
          short8 kf = *(const short8*)&K0[(n * 16 + lq) * 128 + ((ks * 32 + lk * 8) ^ rsw)];
          saccA[n] = __builtin_amdgcn_mfma_f32_16x16x32_bf16(qfA[ks], kf, saccA[n], 0, 0, 0);
        }
    }
    if (t == qtA) {
#pragma unroll
      for (int n = 0; n < 4; n++)
#pragma unroll
        for (int r = 0; r < 4; r++) {
          int qrow = q0A + w * 16 + lk * 4 + r;
          int kvc = kv0 + n * 16 + lq;
          if (kvc > qrow) saccA[n][r] = -3.0e38f;
        }
    }
    attn_sm_pv(saccA, accoA, rmA, rsA, Ps[w], V0, lq, lk, rsw);
    if (actB) {
      if (t == qtB) {
#pragma unroll
        for (int n = 0; n < 4; n++)
#pragma unroll
          for (int r = 0; r < 4; r++) {
            int qrow = q0B + w * 16 + lk * 4 + r;
            int kvc = kv0 + n * 16 + lq;
            if (kvc > qrow) saccB[n][r] = -3.0e38f;
          }
      }
      attn_sm_pv(saccB, accoB, rmB, rsB, Ps[w], V0, lq, lk, rsw);
    }
    __syncthreads();   // drain next-tile DMA + barrier; buf ready
    cur ^= 1;
  }

  // final cross-lane sum reduce (deferred), then normalize + store
#pragma unroll
  for (int r = 0; r < 4; r++) {
    float sA = rsA[r];
    sA += __shfl_xor(sA, 1, 64);
    sA += __shfl_xor(sA, 2, 64);
    sA += __shfl_xor(sA, 4, 64);
    sA += __shfl_xor(sA, 8, 64);
    float invA = 1.0f / sA;
    int srowA = q0A + w * 16 + lk * 4 + r;
    unsigned short* dstA = ob + ((size_t)b * S_LEN + srowA) * DMODEL + h * HDIM;
#pragma unroll
    for (int nd = 0; nd < 8; nd++) dstA[nd * 16 + lq] = f2bf(accoA[nd][r] * invA);
    float sB = rsB[r];
    sB += __shfl_xor(sB, 1, 64);
    sB += __shfl_xor(sB, 2, 64);
    sB += __shfl_xor(sB, 4, 64);
    sB += __shfl_xor(sB, 8, 64);
    float invB = 1.0f / sB;
    int srowB = q0B + w * 16 + lk * 4 + r;
    unsigned short* dstB = ob + ((size_t)b * S_LEN + srowB) * DMODEL + h * HDIM;
#pragma unroll
    for (int nd = 0; nd < 8; nd++) dstB[nd * 16 + lq] = f2bf(accoB[nd][r] * invB);
  }
}

// ---------------- output projection GEMM (fp32 out) ----------------
__global__ __launch_bounds__(256) void k_gemm_out(
    const unsigned short* __restrict__ ob, const unsigned short* __restrict__ wob,
    const float* __restrict__ bo, float* __restrict__ out) {
  __shared__ unsigned short As[128][64];
  __shared__ unsigned short Bs[128][64];
  int m0 = blockIdx.x * 128, n0 = blockIdx.y * 128;   // plain mapping
  int tid = threadIdx.x, lane = tid & 63, wid = tid >> 6;
  int wr = wid >> 1, wc = wid & 1;
  int lq = lane & 15, lk = lane >> 4;
  int gr = wid * 32 + (lane >> 3);
  int gc = ((lane & 7) * 8) ^ ((lane >> 3) << 3);

  f32x4 acc[4][4];
#pragma unroll
  for (int m = 0; m < 4; m++)
#pragma unroll
    for (int n = 0; n < 4; n++) { acc[m][n][0]=0.f; acc[m][n][1]=0.f; acc[m][n][2]=0.f; acc[m][n][3]=0.f; }

  for (int k0 = 0; k0 < DMODEL; k0 += 64) {
#pragma unroll
    for (int i = 0; i < 4; i++) {
      gl_lds16(ob  + (size_t)(m0 + gr + i * 8) * DMODEL + k0 + gc, &As[wid * 32 + i * 8][0]);
      gl_lds16(wob + (size_t)(n0 + gr + i * 8) * DMODEL + k0 + gc, &Bs[wid * 32 + i * 8][0]);
    }
    __syncthreads();
#pragma unroll
    for (int kk = 0; kk < 2; kk++) {
      short8 af[4], bfr[4];
      int sw = (lq & 7) << 3;
#pragma unroll
      for (int m = 0; m < 4; m++)
        af[m] = *(const short8*)&As[wr * 64 + m * 16 + lq][(kk * 32 + lk * 8) ^ sw];
#pragma unroll
      for (int n = 0; n < 4; n++)
        bfr[n] = *(const short8*)&Bs[wc * 64 + n * 16 + lq][(kk * 32 + lk * 8) ^ sw];
#pragma unroll
      for (int m = 0; m < 4; m++)
#pragma unroll
        for (int n = 0; n < 4; n++)
          acc[m][n] = __builtin_amdgcn_mfma_f32_16x16x32_bf16(af[m], bfr[n], acc[m][n], 0, 0, 0);
    }
    __syncthreads();
  }
#pragma unroll
  for (int n = 0; n < 4; n++) {
    int el = n0 + wc * 64 + n * 16 + lq;
    float bi = bo[el];
#pragma unroll
    for (int m = 0; m < 4; m++) {
      int row = m0 + wr * 64 + m * 16 + lk * 4;
#pragma unroll
      for (int r = 0; r < 4; r++)
        out[(size_t)(row + r) * DMODEL + el] = acc[m][n][r] + bi;
    }
  }
}

extern "C" void kernel_launch(void* const* d_in, const int* in_sizes, int n_in,
                              void* d_out, int out_size, void* d_ws, size_t ws_size,
                              hipStream_t stream) {
  const float* x  = (const float*)d_in[0];
  const float* Wq = (const float*)d_in[2];
  const float* bq = (const float*)d_in[3];
  const float* Wk = (const float*)d_in[4];
  const float* bk = (const float*)d_in[5];
  const float* Wv = (const float*)d_in[6];
  const float* bv = (const float*)d_in[7];
  const float* Wo = (const float*)d_in[8];
  const float* bo = (const float*)d_in[9];
  float* out = (float*)d_out;
  char* ws = (char*)d_ws;

  unsigned short* xb  = (unsigned short*)(ws + XB_OFF);
  unsigned short* wqb = (unsigned short*)(ws + WQ_OFF);
  unsigned short* wkb = (unsigned short*)(ws + WK_OFF);
  unsigned short* wvb = (unsigned short*)(ws + WV_OFF);
  unsigned short* qr  = (unsigned short*)(ws + Q_OFF);
  unsigned short* kr  = (unsigned short*)(ws + K_OFF);
  unsigned short* vt  = (unsigned short*)(ws + VT_OFF);
  float* ct = (float*)(ws + COS_OFF);
  float* st = (float*)(ws + SIN_OFF);
  bool haveWo = (ws_size >= WS_NEED);
  unsigned short* wob = haveWo ? (unsigned short*)(ws + WO_OFF) : nullptr;

  // x + Wq/Wk/Wv (+Wo if slot fits) converts + rope table, one launch
  k_prep<<<25088, 256, 0, stream>>>(x, Wq, Wk, Wv, Wo, xb, wqb, wkb, wvb, wob, ct, st);
  // fused QKV projection + RoPE + layout transform (Q scaled by 1/sqrt(128))
  k_gemm_qkv<<<dim3(MROWS / 128, 6144 / 128), 256, 0, stream>>>(
      xb, wqb, wkb, wvb, bq, bk, bv, ct, st, qr, kr, vt);
  if (!haveWo)
    k_cvt<<<(DMODEL * DMODEL / 4 + 255) / 256, 256, 0, stream>>>(Wo, wqb, DMODEL * DMODEL / 4);
  k_attn<<<dim3(BHTOT, 16), 256, 0, stream>>>(qr, kr, vt, xb);
  k_gemm_out<<<dim3(MROWS / 128, DMODEL / 128), 256, 0, stream>>>(
      xb, haveWo ? wob : wqb, bo, out);
}

// Round 9
// 231.853 us; speedup vs baseline: 1.8780x; 1.1183x over previous
//
#include <hip/hip_runtime.h>
#include <stdint.h>
#include <math.h>

typedef short short8 __attribute__((ext_vector_type(8)));
typedef float f32x4 __attribute__((ext_vector_type(4)));

// Problem constants
#define S_LEN   2048
#define DMODEL  2048
#define NHEADS  16
#define HDIM    128
#define NBATCH  2
#define BHTOT   32      // NBATCH*NHEADS
#define MROWS   4096    // NBATCH*S_LEN

// Workspace byte offsets
#define XB_OFF   ((size_t)0)          // x bf16; reused as attn-output O
#define WQ_OFF   ((size_t)16777216)   // Wq bf16; reused for Wo bf16 (fallback path)
#define WK_OFF   ((size_t)25165824)
#define WV_OFF   ((size_t)33554432)
#define Q_OFF    ((size_t)41943040)   // (bh,s,d) bf16
#define K_OFF    ((size_t)58720256)   // (bh,s,d) bf16
#define VT_OFF   ((size_t)75497472)   // (bh,d,s) bf16 (V pre-transposed)
#define COS_OFF  ((size_t)92274688)   // 2048*64 f32
#define SIN_OFF  ((size_t)92798976)   // 2048*64 f32
#define WO_OFF   ((size_t)93323264)   // dedicated Wo bf16 slot (if ws_size permits)
#define WS_NEED  (WO_OFF + (size_t)8388608)

__device__ __forceinline__ unsigned short f2bf(float f) {
  unsigned int u = __float_as_uint(f);
  unsigned int r = (u + 0x7FFFu + ((u >> 16) & 1u)) >> 16;  // RTNE
  return (unsigned short)r;
}
__device__ __forceinline__ float bf2f(unsigned short b) {
  return __uint_as_float(((unsigned int)b) << 16);
}

// async global->LDS, 16B per lane; LDS dest = wave-uniform base + lane*16
__device__ __forceinline__ void gl_lds16(const unsigned short* g, unsigned short* l) {
  __builtin_amdgcn_global_load_lds(
      (const __attribute__((address_space(1))) unsigned int*)(g),
      (__attribute__((address_space(3))) unsigned int*)(l),
      16, 0, 0);
}

// ---------------- fp32 -> bf16 convert (fallback for Wo) ----------------
__global__ __launch_bounds__(256) void k_cvt(const float* __restrict__ src,
                                             unsigned short* __restrict__ dst, int n4) {
  int i = blockIdx.x * 256 + threadIdx.x;
  if (i >= n4) return;
  float4 v = ((const float4*)src)[i];
  ushort4 o;
  o.x = f2bf(v.x); o.y = f2bf(v.y); o.z = f2bf(v.z); o.w = f2bf(v.w);
  ((ushort4*)dst)[i] = o;
}

// ---------------- merged prep: x->bf16, Wq/Wk/Wv(/Wo)->bf16, RoPE table ----------------
__global__ __launch_bounds__(256) void k_prep(
    const float* __restrict__ x, const float* __restrict__ Wq,
    const float* __restrict__ Wk, const float* __restrict__ Wv,
    const float* __restrict__ Wo,
    unsigned short* __restrict__ xb, unsigned short* __restrict__ wqb,
    unsigned short* __restrict__ wkb, unsigned short* __restrict__ wvb,
    unsigned short* __restrict__ wob,   // null if no dedicated slot
    float* __restrict__ ct, float* __restrict__ st) {
  int i = blockIdx.x * 256 + threadIdx.x;
  if (i < 6291456) {                       // float4 converts: x (2^21) + 4 W (2^20 each)
    const float* s; unsigned short* d; int off;
    if (i < 2097152) { s = x; d = xb; off = i; }
    else {
      int j = i - 2097152, sel = j >> 20;
      off = j & 1048575;
      if (sel == 3) {
        if (!wob) return;                  // fallback: separate k_cvt handles Wo
        s = Wo; d = wob;
      } else {
        s = (sel == 0) ? Wq : (sel == 1 ? Wk : Wv);
        d = (sel == 0) ? wqb : (sel == 1 ? wkb : wvb);
      }
    }
    float4 v = ((const float4*)s)[off];
    ushort4 o;
    o.x = f2bf(v.x); o.y = f2bf(v.y); o.z = f2bf(v.z); o.w = f2bf(v.w);
    ((ushort4*)d)[off] = o;
  } else {
    int j = i - 6291456;                   // 2048*64 rope table entries
    if (j < S_LEN * 64) {
      int s = j >> 6, jj = j & 63;
      float inv = expf(-(float)(2 * jj) * (9.210340371976184f / 128.0f));
      float ang = (float)s * inv;
      ct[j] = cosf(ang);
      st[j] = sinf(ang);
    }
  }
}

// ---------------- fused QKV projection GEMM + RoPE + transpose epilogue ----------------
// T3 minimum-2-phase: double-buffered global_load_lds staging (issue next K-tile's
// DMA before computing current; ONE barrier per K-step). LDS 64 KB -> 2 blocks/CU,
// equal to the existing register cap (112 VGPR + 64 AGPR), so no occupancy loss.
#define CP 136
__global__ __launch_bounds__(256) void k_gemm_qkv(
    const unsigned short* __restrict__ xb,
    const unsigned short* __restrict__ wqb, const unsigned short* __restrict__ wkb,
    const unsigned short* __restrict__ wvb,
    const float* __restrict__ bq, const float* __restrict__ bk, const float* __restrict__ bv,
    const float* __restrict__ ct, const float* __restrict__ st,
    unsigned short* __restrict__ qr, unsigned short* __restrict__ kr,
    unsigned short* __restrict__ vt) {
  __shared__ unsigned short SMEM[32768];   // 64 KB: buf0 A[0,8192) B[8192,16384); buf1 +16384
  int m0 = blockIdx.x * 128;
  int n0g = blockIdx.y * 128;              // 0..6143
  int wsel = n0g >> 11;                    // 0=Q 1=K 2=V
  int nw0 = n0g & (DMODEL - 1);
  const unsigned short* W = (wsel == 0) ? wqb : (wsel == 1 ? wkb : wvb);
  const float* bias = (wsel == 0) ? bq : (wsel == 1 ? bk : bv);
  int tid = threadIdx.x, lane = tid & 63, wid = tid >> 6;
  int wr = wid >> 1, wc = wid & 1;
  int lq = lane & 15, lk = lane >> 4;
  int gr = wid * 32 + (lane >> 3);                       // staging row (i=0)
  int gc = ((lane & 7) * 8) ^ ((lane >> 3) << 3);        // pre-swizzled source col
  int lbase = (wid * 32) * 64;                           // wave-uniform LDS elem offset

  f32x4 acc[4][4];
#pragma unroll
  for (int m = 0; m < 4; m++)
#pragma unroll
    for (int n = 0; n < 4; n++) { acc[m][n][0]=0.f; acc[m][n][1]=0.f; acc[m][n][2]=0.f; acc[m][n][3]=0.f; }

  // prologue: stage K-tile 0 into buf 0
#pragma unroll
  for (int i = 0; i < 4; i++) {
    gl_lds16(xb + (size_t)(m0 + gr + i * 8) * DMODEL + gc, SMEM + lbase + i * 512);
    gl_lds16(W  + (size_t)(nw0 + gr + i * 8) * DMODEL + gc, SMEM + 8192 + lbase + i * 512);
  }
  __syncthreads();
  int cur = 0;

  for (int k0 = 0; k0 < DMODEL; k0 += 64) {
    // issue next tile's DMA into buf^1 (in flight across this tile's compute)
    if (k0 + 64 < DMODEL) {
      int kn = k0 + 64;
      unsigned short* An = SMEM + (cur ^ 1) * 16384;
#pragma unroll
      for (int i = 0; i < 4; i++) {
        gl_lds16(xb + (size_t)(m0 + gr + i * 8) * DMODEL + kn + gc, An + lbase + i * 512);
        gl_lds16(W  + (size_t)(nw0 + gr + i * 8) * DMODEL + kn + gc, An + 8192 + lbase + i * 512);
      }
    }
    const unsigned short* Ac = SMEM + cur * 16384;
    const unsigned short* Bc = Ac + 8192;
#pragma unroll
    for (int kk = 0; kk < 2; kk++) {
      short8 af[4], bfr[4];
      int sw = (lq & 7) << 3;
#pragma unroll
      for (int m = 0; m < 4; m++)
        af[m] = *(const short8*)&Ac[(wr * 64 + m * 16 + lq) * 64 + ((kk * 32 + lk * 8) ^ sw)];
#pragma unroll
      for (int n = 0; n < 4; n++)
        bfr[n] = *(const short8*)&Bc[(wc * 64 + n * 16 + lq) * 64 + ((kk * 32 + lk * 8) ^ sw)];
#pragma unroll
      for (int m = 0; m < 4; m++)
#pragma unroll
        for (int n = 0; n < 4; n++)
          acc[m][n] = __builtin_amdgcn_mfma_f32_16x16x32_bf16(af[m], bfr[n], acc[m][n], 0, 0, 0);
    }
    __syncthreads();   // drain next-tile DMA + all reads of buf[cur] done
    cur ^= 1;
  }

  // ---- epilogue: bias (+RoPE for Q/K) -> SMEM[0,17408) in target layout -> coalesced store
  int h = nw0 >> 7, b = m0 >> 11, s0 = m0 & (S_LEN - 1);
  float bi[4];
#pragma unroll
  for (int n = 0; n < 4; n++) bi[n] = bias[nw0 + wc * 64 + n * 16 + lq];

  if (wsel < 2) {
    float qs = (wsel == 0) ? 0.08838834764831843f : 1.0f;
    if (wc == 0) {
#pragma unroll
      for (int m = 0; m < 4; m++) {
        int sl = wr * 64 + m * 16 + lk * 4;
#pragma unroll
        for (int r = 0; r < 4; r++) {
          int s = (s0 + sl + r);
          const float* cb = ct + s * 64;
          const float* sb = st + s * 64;
#pragma unroll
          for (int n = 0; n < 2; n++) {
            int fq = n * 16 + lq;
            float x1 = acc[m][n][r] + bi[n];
            float x2 = acc[m][n + 2][r] + bi[n + 2];
            SMEM[(sl + r) * CP + fq]      = f2bf((x1 * cb[fq]      - x2 * sb[fq])      * qs);
            SMEM[(sl + r) * CP + fq + 32] = f2bf((x2 * cb[fq + 32] + x1 * sb[fq + 32]) * qs);
          }
        }
      }
    } else {
#pragma unroll
      for (int m = 0; m < 4; m++) {
        int sl = wr * 64 + m * 16 + lk * 4;
#pragma unroll
        for (int n = 0; n < 4; n++) {
          int fq = 64 + n * 16 + lq;
#pragma unroll
          for (int r = 0; r < 4; r++)
            SMEM[(sl + r) * CP + fq] = f2bf((acc[m][n][r] + bi[n]) * qs);
        }
      }
    }
    __syncthreads();
    int row = tid >> 1, hf2 = tid & 1;
    unsigned short* dstb = (wsel == 0 ? qr : kr) +
        ((size_t)(b * NHEADS + h) * S_LEN + s0 + row) * HDIM + hf2 * 64;
    const unsigned short* srcb = &SMEM[row * CP + hf2 * 64];
#pragma unroll
    for (int j = 0; j < 8; j++)
      *(short8*)(dstb + j * 8) = *(const short8*)(srcb + j * 8);
  } else {
#pragma unroll
    for (int m = 0; m < 4; m++) {
      int sl = wr * 64 + m * 16 + lk * 4;
#pragma unroll
      for (int n = 0; n < 4; n++) {
        int fq = wc * 64 + n * 16 + lq;
#pragma unroll
        for (int r = 0; r < 4; r++)
          SMEM[fq * CP + sl + r] = f2bf(acc[m][n][r] + bi[n]);
      }
    }
    __syncthreads();
    int row = tid >> 1, hf2 = tid & 1;
    unsigned short* dstb = vt +
        ((size_t)(b * NHEADS + h) * HDIM + row) * S_LEN + s0 + hf2 * 64;
    const unsigned short* srcb = &SMEM[row * CP + hf2 * 64];
#pragma unroll
    for (int j = 0; j < 8; j++)
      *(short8*)(dstb + j * 8) = *(const short8*)(srcb + j * 8);
  }
}

// ---------------- attn per-tile softmax (defer-max, per-lane partial sums) ----------------
__device__ __forceinline__ void attn_sm_pv(
    f32x4* sacc, f32x4* acco, float* rm, float* rs,
    unsigned short (*Psw)[72], const unsigned short* V0,
    int lq, int lk, int rsw) {
  float mx4[4];
  int need = 0;
#pragma unroll
  for (int r = 0; r < 4; r++) {
    float mx = fmaxf(fmaxf(sacc[0][r], sacc[1][r]), fmaxf(sacc[2][r], sacc[3][r]));
    mx = fmaxf(mx, __shfl_xor(mx, 1, 64));
    mx = fmaxf(mx, __shfl_xor(mx, 2, 64));
    mx = fmaxf(mx, __shfl_xor(mx, 4, 64));
    mx = fmaxf(mx, __shfl_xor(mx, 8, 64));
    mx4[r] = mx;
    need |= (mx - rm[r] > 8.0f) ? 1 : 0;
  }
  if (__any(need)) {
#pragma unroll
    for (int r = 0; r < 4; r++) {
      float mnew = fmaxf(rm[r], mx4[r]);
      float corr = __expf(rm[r] - mnew);
      rs[r] *= corr;
#pragma unroll
      for (int nd = 0; nd < 8; nd++) acco[nd][r] *= corr;
      rm[r] = mnew;
    }
  }
#pragma unroll
  for (int r = 0; r < 4; r++) {
    float psum = 0.f;
#pragma unroll
    for (int n = 0; n < 4; n++) {
      float p = __expf(sacc[n][r] - rm[r]);
      sacc[n][r] = p;
      psum += p;
    }
    rs[r] += psum;                         // per-lane partial; cross-lane reduce at end
  }
#pragma unroll
  for (int n = 0; n < 4; n++)
#pragma unroll
    for (int r = 0; r < 4; r++)
      Psw[lk * 4 + r][n * 16 + lq] = f2bf(sacc[n][r]);
#pragma unroll
  for (int ks2 = 0; ks2 < 2; ks2++) {
    short8 pa = *(const short8*)&Psw[lq][ks2 * 32 + lk * 8];
#pragma unroll
    for (int nd = 0; nd < 8; nd++) {
      short8 vf = *(const short8*)&V0[(nd * 16 + lq) * 64 + ((ks2 * 32 + lk * 8) ^ rsw)];
      acco[nd] = __builtin_amdgcn_mfma_f32_16x16x32_bf16(pa, vf, acco[nd], 0, 0, 0);
    }
  }
}

// ---------------- causal flash attention (merged dual-q-tile sweep) ----------------
__global__ __launch_bounds__(256, 2) void k_attn(
    const unsigned short* __restrict__ qr, const unsigned short* __restrict__ kr,
    const unsigned short* __restrict__ vt, unsigned short* __restrict__ ob) {
  __shared__ unsigned short Kl[2][64 * 128];   // [kv][d] swizzled flat, dbuf
  __shared__ unsigned short Vl[2][128 * 64];   // [d][kv] swizzled flat, dbuf
  __shared__ unsigned short Ps[4][16][72];     // per-wave P round-trip
  int bh = blockIdx.x;
  int yy = blockIdx.y;
  int f = (yy < 8) ? yy : 23 - yy;             // bijective over 0..15
  int qtA = 31 - f, qtB = f;
  int q0A = qtA * 64, q0B = qtB * 64;
  int b = bh >> 4, h = bh & 15;
  int tid = threadIdx.x, lane = tid & 63, w = tid >> 6;
  int lq = lane & 15, lk = lane >> 4;
  const unsigned short* kbh = kr + (size_t)bh * S_LEN * HDIM;
  const unsigned short* vbh = vt + (size_t)bh * HDIM * S_LEN;
  int ksrow = tid >> 4;
  int kscol = ((tid & 15) * 8) ^ ((ksrow & 7) << 3);
  int vsrow = tid >> 3;
  int vscol = ((tid & 7) * 8) ^ ((vsrow & 7) << 3);
  int ldso = tid * 8;
  int rsw = (lq & 7) << 3;

  const unsigned short* qbA =
      qr + ((size_t)bh * S_LEN + q0A + w * 16 + lq) * HDIM + lk * 8;
  const unsigned short* qbB =
      qr + ((size_t)bh * S_LEN + q0B + w * 16 + lq) * HDIM + lk * 8;
  short8 qfA[4], qfB[4];
#pragma unroll
  for (int ks = 0; ks < 4; ks++) {
    qfA[ks] = *(const short8*)(qbA + ks * 32);
    qfB[ks] = *(const short8*)(qbB + ks * 32);
  }

  f32x4 accoA[8], accoB[8];
#pragma unroll
  for (int nd = 0; nd < 8; nd++) {
    accoA[nd][0]=0.f; accoA[nd][1]=0.f; accoA[nd][2]=0.f; accoA[nd][3]=0.f;
    accoB[nd][0]=0.f; accoB[nd][1]=0.f; accoB[nd][2]=0.f; accoB[nd][3]=0.f;
  }
  float rmA[4], rsA[4], rmB[4], rsB[4];
#pragma unroll
  for (int r = 0; r < 4; r++) { rmA[r] = -3.0e38f; rsA[r] = 0.f; rmB[r] = -3.0e38f; rsB[r] = 0.f; }

  // prologue: stage tile 0 into buf 0
#pragma unroll
  for (int c = 0; c < 4; c++) {
    gl_lds16(kbh + (size_t)(c * 16 + ksrow) * HDIM + kscol, &Kl[0][c * 2048 + ldso]);
    gl_lds16(vbh + (size_t)(c * 32 + vsrow) * S_LEN + vscol, &Vl[0][c * 2048 + ldso]);
  }
  __syncthreads();
  int cur = 0;

  for (int t = 0; t <= qtA; t++) {
    int kv0 = t * 64;
    if (t < qtA) {
      int nx = kv0 + 64;
#pragma unroll
      for (int c = 0; c < 4; c++) {
        gl_lds16(kbh + (size_t)(nx + c * 16 + ksrow) * HDIM + kscol,
                 &Kl[cur ^ 1][c * 2048 + ldso]);
        gl_lds16(vbh + (size_t)(c * 32 + vsrow) * S_LEN + nx + vscol,
                 &Vl[cur ^ 1][c * 2048 + ldso]);
      }
    }
    const unsigned short* K0 = &Kl[cur][0];
    const unsigned short* V0 = &Vl[cur][0];
    bool actB = (t <= qtB);

    f32x4 saccA[4], saccB[4];
#pragma unroll
    for (int n = 0; n < 4; n++) {
      saccA[n][0]=0.f; saccA[n][1]=0.f; saccA[n][2]=0.f; saccA[n][3]=0.f;
      saccB[n][0]=0.f; saccB[n][1]=0.f; saccB[n][2]=0.f; saccB[n][3]=0.f;
    }
    if (actB) {
#pragma unroll
      for (int ks = 0; ks < 4; ks++)
#pragma unroll
        for (int n = 0; n < 4; n++) {
          short8 kf = *(const short8*)&K0[(n * 16 + lq) * 128 + ((ks * 32 + lk * 8) ^ rsw)];
          saccA[n] = __builtin_amdgcn_mfma_f32_16x16x32_bf16(qfA[ks], kf, saccA[n], 0, 0, 0);
          saccB[n] = __builtin_amdgcn_mfma_f32_16x16x32_bf16(qfB[ks], kf, saccB[n], 0, 0, 0);
        }
    } else {
#pragma unroll
      for (int ks = 0; ks < 4; ks++)
#pragma unroll
        for (int n = 0; n < 4; n++) {
          short8 kf = *(const short8*)&K0[(n * 16 + lq) * 128 + ((ks * 32 + lk * 8) ^ rsw)];
          saccA[n] = __builtin_amdgcn_mfma_f32_16x16x32_bf16(qfA[ks], kf, saccA[n], 0, 0, 0);
        }
    }
    if (t == qtA) {
#pragma unroll
      for (int n = 0; n < 4; n++)
#pragma unroll
        for (int r = 0; r < 4; r++) {
          int qrow = q0A + w * 16 + lk * 4 + r;
          int kvc = kv0 + n * 16 + lq;
          if (kvc > qrow) saccA[n][r] = -3.0e38f;
        }
    }
    attn_sm_pv(saccA, accoA, rmA, rsA, Ps[w], V0, lq, lk, rsw);
    if (actB) {
      if (t == qtB) {
#pragma unroll
        for (int n = 0; n < 4; n++)
#pragma unroll
          for (int r = 0; r < 4; r++) {
            int qrow = q0B + w * 16 + lk * 4 + r;
            int kvc = kv0 + n * 16 + lq;
            if (kvc > qrow) saccB[n][r] = -3.0e38f;
          }
      }
      attn_sm_pv(saccB, accoB, rmB, rsB, Ps[w], V0, lq, lk, rsw);
    }
    __syncthreads();   // drain next-tile DMA + barrier; buf ready
    cur ^= 1;
  }

  // final cross-lane sum reduce (deferred), then normalize + store
#pragma unroll
  for (int r = 0; r < 4; r++) {
    float sA = rsA[r];
    sA += __shfl_xor(sA, 1, 64);
    sA += __shfl_xor(sA, 2, 64);
    sA += __shfl_xor(sA, 4, 64);
    sA += __shfl_xor(sA, 8, 64);
    float invA = 1.0f / sA;
    int srowA = q0A + w * 16 + lk * 4 + r;
    unsigned short* dstA = ob + ((size_t)b * S_LEN + srowA) * DMODEL + h * HDIM;
#pragma unroll
    for (int nd = 0; nd < 8; nd++) dstA[nd * 16 + lq] = f2bf(accoA[nd][r] * invA);
    float sB = rsB[r];
    sB += __shfl_xor(sB, 1, 64);
    sB += __shfl_xor(sB, 2, 64);
    sB += __shfl_xor(sB, 4, 64);
    sB += __shfl_xor(sB, 8, 64);
    float invB = 1.0f / sB;
    int srowB = q0B + w * 16 + lk * 4 + r;
    unsigned short* dstB = ob + ((size_t)b * S_LEN + srowB) * DMODEL + h * HDIM;
#pragma unroll
    for (int nd = 0; nd < 8; nd++) dstB[nd * 16 + lq] = f2bf(accoB[nd][r] * invB);
  }
}

// ---------------- output projection GEMM (T3 2-phase dbuf, fp32 out) ----------------
__global__ __launch_bounds__(256) void k_gemm_out(
    const unsigned short* __restrict__ ob, const unsigned short* __restrict__ wob,
    const float* __restrict__ bo, float* __restrict__ out) {
  __shared__ unsigned short SMEM[32768];   // 64 KB dbuf
  int m0 = blockIdx.x * 128, n0 = blockIdx.y * 128;
  int tid = threadIdx.x, lane = tid & 63, wid = tid >> 6;
  int wr = wid >> 1, wc = wid & 1;
  int lq = lane & 15, lk = lane >> 4;
  int gr = wid * 32 + (lane >> 3);
  int gc = ((lane & 7) * 8) ^ ((lane >> 3) << 3);
  int lbase = (wid * 32) * 64;

  f32x4 acc[4][4];
#pragma unroll
  for (int m = 0; m < 4; m++)
#pragma unroll
    for (int n = 0; n < 4; n++) { acc[m][n][0]=0.f; acc[m][n][1]=0.f; acc[m][n][2]=0.f; acc[m][n][3]=0.f; }

  // prologue: stage K-tile 0 into buf 0
#pragma unroll
  for (int i = 0; i < 4; i++) {
    gl_lds16(ob  + (size_t)(m0 + gr + i * 8) * DMODEL + gc, SMEM + lbase + i * 512);
    gl_lds16(wob + (size_t)(n0 + gr + i * 8) * DMODEL + gc, SMEM + 8192 + lbase + i * 512);
  }
  __syncthreads();
  int cur = 0;

  for (int k0 = 0; k0 < DMODEL; k0 += 64) {
    if (k0 + 64 < DMODEL) {
      int kn = k0 + 64;
      unsigned short* An = SMEM + (cur ^ 1) * 16384;
#pragma unroll
      for (int i = 0; i < 4; i++) {
        gl_lds16(ob  + (size_t)(m0 + gr + i * 8) * DMODEL + kn + gc, An + lbase + i * 512);
        gl_lds16(wob + (size_t)(n0 + gr + i * 8) * DMODEL + kn + gc, An + 8192 + lbase + i * 512);
      }
    }
    const unsigned short* Ac = SMEM + cur * 16384;
    const unsigned short* Bc = Ac + 8192;
#pragma unroll
    for (int kk = 0; kk < 2; kk++) {
      short8 af[4], bfr[4];
      int sw = (lq & 7) << 3;
#pragma unroll
      for (int m = 0; m < 4; m++)
        af[m] = *(const short8*)&Ac[(wr * 64 + m * 16 + lq) * 64 + ((kk * 32 + lk * 8) ^ sw)];
#pragma unroll
      for (int n = 0; n < 4; n++)
        bfr[n] = *(const short8*)&Bc[(wc * 64 + n * 16 + lq) * 64 + ((kk * 32 + lk * 8) ^ sw)];
#pragma unroll
      for (int m = 0; m < 4; m++)
#pragma unroll
        for (int n = 0; n < 4; n++)
          acc[m][n] = __builtin_amdgcn_mfma_f32_16x16x32_bf16(af[m], bfr[n], acc[m][n], 0, 0, 0);
    }
    __syncthreads();
    cur ^= 1;
  }
#pragma unroll
  for (int n = 0; n < 4; n++) {
    int el = n0 + wc * 64 + n * 16 + lq;
    float bi = bo[el];
#pragma unroll
    for (int m = 0; m < 4; m++) {
      int row = m0 + wr * 64 + m * 16 + lk * 4;
#pragma unroll
      for (int r = 0; r < 4; r++)
        out[(size_t)(row + r) * DMODEL + el] = acc[m][n][r] + bi;
    }
  }
}

extern "C" void kernel_launch(void* const* d_in, const int* in_sizes, int n_in,
                              void* d_out, int out_size, void* d_ws, size_t ws_size,
                              hipStream_t stream) {
  const float* x  = (const float*)d_in[0];
  const float* Wq = (const float*)d_in[2];
  const float* bq = (const float*)d_in[3];
  const float* Wk = (const float*)d_in[4];
  const float* bk = (const float*)d_in[5];
  const float* Wv = (const float*)d_in[6];
  const float* bv = (const float*)d_in[7];
  const float* Wo = (const float*)d_in[8];
  const float* bo = (const float*)d_in[9];
  float* out = (float*)d_out;
  char* ws = (char*)d_ws;

  unsigned short* xb  = (unsigned short*)(ws + XB_OFF);
  unsigned short* wqb = (unsigned short*)(ws + WQ_OFF);
  unsigned short* wkb = (unsigned short*)(ws + WK_OFF);
  unsigned short* wvb = (unsigned short*)(ws + WV_OFF);
  unsigned short* qr  = (unsigned short*)(ws + Q_OFF);
  unsigned short* kr  = (unsigned short*)(ws + K_OFF);
  unsigned short* vt  = (unsigned short*)(ws + VT_OFF);
  float* ct = (float*)(ws + COS_OFF);
  float* st = (float*)(ws + SIN_OFF);
  bool haveWo = (ws_size >= WS_NEED);
  unsigned short* wob = haveWo ? (unsigned short*)(ws + WO_OFF) : nullptr;

  // x + Wq/Wk/Wv (+Wo if slot fits) converts + rope table, one launch
  k_prep<<<25088, 256, 0, stream>>>(x, Wq, Wk, Wv, Wo, xb, wqb, wkb, wvb, wob, ct, st);
  // fused QKV projection + RoPE + layout transform (Q scaled by 1/sqrt(128))
  k_gemm_qkv<<<dim3(MROWS / 128, 6144 / 128), 256, 0, stream>>>(
      xb, wqb, wkb, wvb, bq, bk, bv, ct, st, qr, kr, vt);
  if (!haveWo)
    k_cvt<<<(DMODEL * DMODEL / 4 + 255) / 256, 256, 0, stream>>>(Wo, wqb, DMODEL * DMODEL / 4);
  k_attn<<<dim3(BHTOT, 16), 256, 0, stream>>>(qr, kr, vt, xb);
  k_gemm_out<<<dim3(MROWS / 128, DMODEL / 128), 256, 0, stream>>>(
      xb, haveWo ? wob : wqb, bo, out);
}